// Round 6
// baseline (452.082 us; speedup 1.0000x reference)
//
#include <hip/hip_runtime.h>
#include <hip/hip_bf16.h>
#include <cmath>

#define NL      6
#define NHEADS  4
#define DIM     128
#define FFD     512
#define CMID_   8
#define COUT_   16
#define QOUT_   10
#define MAXLEN_ 512
#define NCLS_   3
#define BB      32
#define TT      500
#define FIN_    232
#define MM      (BB*TT)
#define HD      32
#define RELLEN  (2*MAXLEN_-1)

typedef __attribute__((ext_vector_type(8))) short short8;
typedef __attribute__((ext_vector_type(4))) float f32x4;
typedef unsigned short ushort_t;

__device__ inline unsigned bf16r(float x) {   // RNE float->bf16 bits (finite inputs)
    unsigned u = __float_as_uint(x);
    return (u + 0x7fffu + ((u >> 16) & 1u)) >> 16;
}

// ---------------- encoder precompute (1 block) ----------------
__global__ __launch_bounds__(128) void enc_pre_kernel(
    const float* __restrict__ proj_w, const float* __restrict__ proj_b,
    const float* __restrict__ queries, const float* __restrict__ fc_w,
    const float* __restrict__ fc_b, const float* __restrict__ embed_w,
    const float* __restrict__ embed_b,
    float* __restrict__ alpha, float* __restrict__ E, float* __restrict__ c0)
{
    __shared__ float pw[CMID_], cb[CMID_], gam[COUT_], del[COUT_];
    int t = threadIdx.x;
    if (t < CMID_) { pw[t] = proj_w[t]; cb[t] = proj_b[t] + ((t & 1) ? 1.f : 0.f); }
    __syncthreads();
    if (t < QOUT_) {
        float a = 0.f;
        for (int c = 0; c < CMID_; ++c) a += pw[c] * queries[t*CMID_ + c];
        alpha[t] = a;
    }
    if (t < COUT_) {
        float gg = 0.f, dd = 0.f;
        for (int c = 0; c < CMID_; ++c) {
            gg += pw[c] * fc_w[c*COUT_ + t];
            dd += cb[c] * fc_w[c*COUT_ + t];
        }
        gam[t] = gg; del[t] = dd + fc_b[t];
    }
    __syncthreads();
    for (int i = t; i < QOUT_*DIM; i += 128) {
        int q = i / DIM, d = i % DIM;
        float e = 0.f;
        for (int o = 0; o < COUT_; ++o) e += gam[o] * embed_w[(o*QOUT_ + q)*DIM + d];
        E[i] = e;
    }
    {
        float c = embed_b[t];
        for (int o = 0; o < COUT_; ++o) {
            float dl = del[o];
            for (int q = 0; q < QOUT_; ++q) c += dl * embed_w[(o*QOUT_ + q)*DIM + t];
        }
        c0[t] = c;
    }
}

// ---------------- encoder main ----------------
__global__ __launch_bounds__(64) void enc_kernel(
    const float* __restrict__ x1, const float* __restrict__ alpha,
    const float* __restrict__ E, const float* __restrict__ c0,
    float* __restrict__ h, ushort_t* __restrict__ hb)
{
    int bt = blockIdx.x;
    int lane = threadIdx.x;
    const float* xr = x1 + (size_t)bt * FIN_;
    float xv[4];
    bool vld[4];
    #pragma unroll
    for (int i = 0; i < 4; ++i) {
        int f = lane + (i << 6);
        vld[i] = (f < FIN_);
        xv[i] = vld[i] ? xr[f] : 0.f;
    }
    float vmax = -INFINITY, vmin = INFINITY;
    #pragma unroll
    for (int i = 0; i < 4; ++i) if (vld[i]) { vmax = fmaxf(vmax, xv[i]); vmin = fminf(vmin, xv[i]); }
    #pragma unroll
    for (int off = 1; off < 64; off <<= 1) {
        vmax = fmaxf(vmax, __shfl_xor(vmax, off));
        vmin = fminf(vmin, __shfl_xor(vmin, off));
    }
    float mq[QOUT_];
    for (int q = 0; q < QOUT_; ++q) {
        float a = alpha[q];
        float Mx = (a >= 0.f) ? a * vmax : a * vmin;
        float se = 0.f, sx = 0.f;
        #pragma unroll
        for (int i = 0; i < 4; ++i) if (vld[i]) {
            float e = __expf(fmaf(a, xv[i], -Mx));
            se += e; sx += e * xv[i];
        }
        #pragma unroll
        for (int off = 1; off < 64; off <<= 1) { se += __shfl_xor(se, off); sx += __shfl_xor(sx, off); }
        mq[q] = sx / se;
    }
    #pragma unroll
    for (int k = 0; k < 2; ++k) {
        int d = lane + (k << 6);
        float hv = c0[d];
        #pragma unroll
        for (int q = 0; q < QOUT_; ++q) hv = fmaf(mq[q], E[q*DIM + d], hv);
        h[(size_t)bt*DIM + d] = hv;
        hb[(size_t)bt*DIM + d] = (ushort_t)bf16r(hv);
    }
}

// ---------------- weight transpose + bf16 convert (once per launch) ----------------
__global__ __launch_bounds__(256) void wtrans_kernel(
    const float* __restrict__ wqkv, const float* __restrict__ wo,
    const float* __restrict__ w1, const float* __restrict__ w2,
    ushort_t* __restrict__ wts)
{
    int bid = blockIdx.x;
    const float* W; ushort_t* Wt; int K, N, tk, tn;
    if (bid < 72) {            // wqkv: K=128,N=384 -> 2x6 tiles x 6 layers
        int l = bid / 12, t = bid % 12; tk = t / 6; tn = t % 6; K = 128; N = 384;
        W = wqkv + (size_t)l*128*384; Wt = wts + (size_t)l*49152;
    } else if (bid < 96) {     // wo: 128x128 -> 2x2 x 6
        int q = bid - 72; int l = q / 4, t = q % 4; tk = t / 2; tn = t % 2; K = 128; N = 128;
        W = wo + (size_t)l*16384; Wt = wts + 294912 + (size_t)l*16384;
    } else if (bid < 192) {    // w1: K=128,N=512 -> 2x8 x 6
        int q = bid - 96; int l = q / 16, t = q % 16; tk = t / 8; tn = t % 8; K = 128; N = 512;
        W = w1 + (size_t)l*65536; Wt = wts + 393216 + (size_t)l*65536;
    } else {                   // w2: K=512,N=128 -> 8x2 x 6
        int q = bid - 192; int l = q / 16, t = q % 16; tk = t / 2; tn = t % 2; K = 512; N = 128;
        W = w2 + (size_t)l*65536; Wt = wts + 786432 + (size_t)l*65536;
    }
    int k0 = tk << 6, n0 = tn << 6;
    __shared__ float Ls[64][65];
    int tid = threadIdx.x;
    #pragma unroll
    for (int i = 0; i < 4; ++i) {
        int id = tid + 256*i;
        int r = id >> 4, ch = id & 15;
        float4 v = *reinterpret_cast<const float4*>(W + (size_t)(k0+r)*N + n0 + ch*4);
        Ls[ch*4+0][r] = v.x; Ls[ch*4+1][r] = v.y; Ls[ch*4+2][r] = v.z; Ls[ch*4+3][r] = v.w;
    }
    __syncthreads();
    #pragma unroll
    for (int i = 0; i < 4; ++i) {
        int id = tid + 256*i;
        int rr = id >> 4, ch = id & 15;
        uint2 o2;
        o2.x = bf16r(Ls[rr][ch*4+0]) | (bf16r(Ls[rr][ch*4+1]) << 16);
        o2.y = bf16r(Ls[rr][ch*4+2]) | (bf16r(Ls[rr][ch*4+3]) << 16);
        *reinterpret_cast<uint2*>(Wt + (size_t)(n0+rr)*K + k0 + ch*4) = o2;
    }
}

// ---------------- bf16 MFMA GEMM (qkv projection) ----------------
template<int BM>
__global__ __launch_bounds__(256) void gemm_mfma_kernel(
    const ushort_t* __restrict__ A, const ushort_t* __restrict__ Wt,
    const float* __restrict__ bias, void* __restrict__ C,
    int N, int K, int relu, int obf16)
{
    constexpr int MREP = BM / 32;
    constexpr int APT  = BM / 32;
    __shared__ __align__(16) ushort_t As[BM * 64];
    __shared__ __align__(16) ushort_t Bs[64 * 64];
    const int tid = threadIdx.x;
    const int row0 = blockIdx.y * BM, col0 = blockIdx.x << 6;
    const int w = tid >> 6, lane = tid & 63, g = lane >> 4, n = lane & 15;
    const int wr = w & 1, wc = w >> 1;
    f32x4 acc[MREP][2];
    #pragma unroll
    for (int mt = 0; mt < MREP; ++mt)
        #pragma unroll
        for (int nt = 0; nt < 2; ++nt) acc[mt][nt] = (f32x4){0.f,0.f,0.f,0.f};

    for (int k0 = 0; k0 < K; k0 += 64) {
        __syncthreads();
        #pragma unroll
        for (int i = 0; i < APT; ++i) {
            int id = tid + 256*i;
            int r = id >> 3, c = id & 7;
            uint4 v = *reinterpret_cast<const uint4*>(A + (size_t)(row0 + r)*K + k0 + c*8);
            *reinterpret_cast<uint4*>(As + r*64 + ((c ^ (r & 7)) << 3)) = v;
        }
        #pragma unroll
        for (int i = 0; i < 2; ++i) {
            int id = tid + 256*i;
            int r = id >> 3, c = id & 7;
            uint4 v = *reinterpret_cast<const uint4*>(Wt + (size_t)(col0 + r)*K + k0 + c*8);
            *reinterpret_cast<uint4*>(Bs + r*64 + ((c ^ (r & 7)) << 3)) = v;
        }
        __syncthreads();
        #pragma unroll
        for (int ks = 0; ks < 2; ++ks) {
            short8 af[MREP], bfr[2];
            #pragma unroll
            for (int mt = 0; mt < MREP; ++mt) {
                int r = wr*(BM/2) + mt*16 + n;
                af[mt] = *reinterpret_cast<const short8*>(As + r*64 + (((ks*4 + g) ^ (r & 7)) << 3));
            }
            #pragma unroll
            for (int nt = 0; nt < 2; ++nt) {
                int r = wc*32 + nt*16 + n;
                bfr[nt] = *reinterpret_cast<const short8*>(Bs + r*64 + (((ks*4 + g) ^ (r & 7)) << 3));
            }
            #pragma unroll
            for (int mt = 0; mt < MREP; ++mt)
                #pragma unroll
                for (int nt = 0; nt < 2; ++nt)
                    acc[mt][nt] = __builtin_amdgcn_mfma_f32_16x16x32_bf16(af[mt], bfr[nt], acc[mt][nt], 0, 0, 0);
        }
    }
    #pragma unroll
    for (int mt = 0; mt < MREP; ++mt) {
        #pragma unroll
        for (int nt = 0; nt < 2; ++nt) {
            int col = col0 + wc*32 + nt*16 + n;
            float bv = bias[col];
            #pragma unroll
            for (int r4 = 0; r4 < 4; ++r4) {
                int row = row0 + wr*(BM/2) + mt*16 + g*4 + r4;
                float v = acc[mt][nt][r4] + bv;
                if (relu) v = fmaxf(v, 0.f);
                if (obf16) ((ushort_t*)C)[(size_t)row*N + col] = (ushort_t)bf16r(v);
                else       ((float*)C)[(size_t)row*N + col] = v;
            }
        }
    }
}

// ---------------- fused attention + wo projection + residual + LN1 ----------------
// grid: BB*16 blocks (b, 32-row q-tile); 512 threads = 8 waves = 4 heads x 2 row-halves.
// Flash loop identical math to the proven attn kernel; then O -> LDS, wo GEMM,
// residual + LN epilogue (gemm_ln structure).
__global__ __launch_bounds__(512, 4) void attn_fused_kernel(
    const ushort_t* __restrict__ qkv, const float* __restrict__ rel,
    const ushort_t* __restrict__ wot, const float* __restrict__ bo,
    float* __restrict__ h, ushort_t* __restrict__ hb,
    const float* __restrict__ lng, const float* __restrict__ lnb)
{
    // smemA: Ks[64][128] (16KB) + Vs[64][128] (16KB)  -> reused as wob[128][128] (32KB)
    // smemB: VB[4][2][2][4][16][8] (16KB)             -> reused as Obuf[32][128] (8KB)
    __shared__ __align__(16) ushort_t smemA[16384];
    __shared__ __align__(16) ushort_t smemB[8192];
    __shared__ float rlbuf[544];
    __shared__ float red[8][32][2];
    __shared__ float stats[32][2];

    const int bid = blockIdx.x;
    const int qt = bid & 15, b = bid >> 4;
    const int tid = threadIdx.x;
    const int w = tid >> 6, lane = tid & 63, g = lane >> 4, n = lane & 15;
    const int hh = w & 3, qh = w >> 2;

    const int rlbase = 480 - qt*32;
    for (int i = tid; i < 531; i += 512) rlbuf[i] = rel[rlbase + i];

    const int qlocal = qh*16 + n;
    const int t_q = qt*32 + qlocal;
    const bool qv = (t_q < TT);
    short8 qf = {0,0,0,0,0,0,0,0};
    if (qv) qf = *reinterpret_cast<const short8*>(qkv + (size_t)(b*TT + t_q)*384 + hh*HD + g*8);

    f32x4 acc0 = {0.f,0.f,0.f,0.f}, acc1 = {0.f,0.f,0.f,0.f};
    float m = -INFINITY, lsum = 0.f;
    const float scale = 0.17677669529663687f;   // 1/sqrt(32)
    const f32x4 zf = {0.f,0.f,0.f,0.f};

    for (int kt = 0; kt < 8; ++kt) {
        const int k0 = kt << 6;
        __syncthreads();                        // prev tile fully consumed (rl on iter0)
        #pragma unroll
        for (int i = 0; i < 4; ++i) {           // stage K[64][128] + V[64][128]
            int id = tid + (i << 9);
            int kv = id >> 10, rid = (id >> 4) & 63, c = id & 15;
            int t = k0 + rid;
            uint4 v = make_uint4(0,0,0,0);
            if (t < TT) v = *reinterpret_cast<const uint4*>(
                qkv + (size_t)(b*TT + t)*384 + 128 + (kv << 7) + c*8);
            *reinterpret_cast<uint4*>(smemA + (kv << 13) + rid*128 + ((c ^ (rid & 7)) << 3)) = v;
        }
        __syncthreads();

        // VB relayout (all heads), concurrent with QK^T+softmax
        #pragma unroll
        for (int i = 0; i < 2; ++i) {
            int id = tid + (i << 9);
            int hd2 = (id >> 8) & 3, kch = (id >> 7) & 1, dh = (id >> 6) & 1;
            int gg = (id >> 4) & 3, nn = id & 15;
            int dim = hd2*32 + dh*16 + nn;
            int ch = dim >> 3, off = dim & 7;
            ushort_t tmp[8];
            #pragma unroll
            for (int j = 0; j < 8; ++j) {
                int r = kch*32 + gg*8 + j;
                tmp[j] = smemA[8192 + r*128 + ((ch ^ (r & 7)) << 3) + off];
            }
            *reinterpret_cast<uint4*>(smemB + (((hd2*2 + kch)*2 + dh)*4 + gg)*128 + nn*8)
                = *reinterpret_cast<uint4*>(tmp);
        }

        // S^T = K . Q^T : 4 tiles of 16 kcols
        f32x4 s[4];
        #pragma unroll
        for (int c = 0; c < 4; ++c) {
            int r = c*16 + n;
            short8 ak = *reinterpret_cast<const short8*>(
                smemA + r*128 + (((hh*4 + g) ^ (r & 7)) << 3));
            s[c] = __builtin_amdgcn_mfma_f32_16x16x32_bf16(ak, qf, zf, 0, 0, 0);
        }

        float sv[16];
        float tmax = -INFINITY;
        #pragma unroll
        for (int c = 0; c < 4; ++c)
            #pragma unroll
            for (int r = 0; r < 4; ++r) {
                int kc = k0 + c*16 + g*4 + r;
                float bia = rlbuf[kc + 31 - qlocal];
                float v = (kc < TT) ? fmaf(s[c][r], scale, bia) : -1e30f;
                sv[c*4 + r] = v;
                tmax = fmaxf(tmax, v);
            }
        tmax = fmaxf(tmax, __shfl_xor(tmax, 16));
        tmax = fmaxf(tmax, __shfl_xor(tmax, 32));
        float mnew = fmaxf(m, tmax);
        float corr = __expf(m - mnew);
        m = mnew;
        float ps = 0.f;
        #pragma unroll
        for (int r = 0; r < 16; ++r) { float e = __expf(sv[r] - mnew); sv[r] = e; ps += e; }
        ps += __shfl_xor(ps, 16);
        ps += __shfl_xor(ps, 32);
        lsum = fmaf(lsum, corr, ps);

        int src0 = n + ((g & 1) << 5);
        int src1 = src0 + 16;
        int t0 = (g < 2);
        union { unsigned wd[4]; short8 v; } PA, PB;
        {
            unsigned pk0lo = bf16r(sv[0]) | (bf16r(sv[1]) << 16);
            unsigned pk0hi = bf16r(sv[2]) | (bf16r(sv[3]) << 16);
            unsigned pk1lo = bf16r(sv[4]) | (bf16r(sv[5]) << 16);
            unsigned pk1hi = bf16r(sv[6]) | (bf16r(sv[7]) << 16);
            unsigned a0 = __shfl((int)pk0lo, src0), c0_ = __shfl((int)pk1lo, src0);
            unsigned a1 = __shfl((int)pk0hi, src0), c1_ = __shfl((int)pk1hi, src0);
            unsigned a2 = __shfl((int)pk0lo, src1), c2_ = __shfl((int)pk1lo, src1);
            unsigned a3 = __shfl((int)pk0hi, src1), c3_ = __shfl((int)pk1hi, src1);
            PA.wd[0] = t0 ? a0 : c0_; PA.wd[1] = t0 ? a1 : c1_;
            PA.wd[2] = t0 ? a2 : c2_; PA.wd[3] = t0 ? a3 : c3_;
        }
        {
            unsigned pk0lo = bf16r(sv[8])  | (bf16r(sv[9])  << 16);
            unsigned pk0hi = bf16r(sv[10]) | (bf16r(sv[11]) << 16);
            unsigned pk1lo = bf16r(sv[12]) | (bf16r(sv[13]) << 16);
            unsigned pk1hi = bf16r(sv[14]) | (bf16r(sv[15]) << 16);
            unsigned a0 = __shfl((int)pk0lo, src0), c0_ = __shfl((int)pk1lo, src0);
            unsigned a1 = __shfl((int)pk0hi, src0), c1_ = __shfl((int)pk1hi, src0);
            unsigned a2 = __shfl((int)pk0lo, src1), c2_ = __shfl((int)pk1lo, src1);
            unsigned a3 = __shfl((int)pk0hi, src1), c3_ = __shfl((int)pk1hi, src1);
            PB.wd[0] = t0 ? a0 : c0_; PB.wd[1] = t0 ? a1 : c1_;
            PB.wd[2] = t0 ? a2 : c2_; PB.wd[3] = t0 ? a3 : c3_;
        }

        __syncthreads();                        // VB ready
        short8 a00 = *reinterpret_cast<const short8*>(smemB + (((hh*2+0)*2+0)*4 + g)*128 + n*8);
        short8 a01 = *reinterpret_cast<const short8*>(smemB + (((hh*2+0)*2+1)*4 + g)*128 + n*8);
        short8 a10 = *reinterpret_cast<const short8*>(smemB + (((hh*2+1)*2+0)*4 + g)*128 + n*8);
        short8 a11 = *reinterpret_cast<const short8*>(smemB + (((hh*2+1)*2+1)*4 + g)*128 + n*8);
        #pragma unroll
        for (int r = 0; r < 4; ++r) { acc0[r] *= corr; acc1[r] *= corr; }
        acc0 = __builtin_amdgcn_mfma_f32_16x16x32_bf16(a00, PA.v, acc0, 0, 0, 0);
        acc0 = __builtin_amdgcn_mfma_f32_16x16x32_bf16(a10, PB.v, acc0, 0, 0, 0);
        acc1 = __builtin_amdgcn_mfma_f32_16x16x32_bf16(a01, PA.v, acc1, 0, 0, 0);
        acc1 = __builtin_amdgcn_mfma_f32_16x16x32_bf16(a11, PB.v, acc1, 0, 0, 0);
    }

    __syncthreads();                            // flash done; smemA/smemB reusable
    {   // O -> Obuf (smemB): row=qlocal, dims hh*32+dh*16+g*4..+3 (packed bf16)
        float inv = qv ? (1.f / lsum) : 0.f;
        #pragma unroll
        for (int dh = 0; dh < 2; ++dh) {
            f32x4 a = dh ? acc1 : acc0;
            int dimb = hh*HD + dh*16 + g*4;
            int ch = dimb >> 3;
            uint2 pk;
            pk.x = bf16r(a[0]*inv) | (bf16r(a[1]*inv) << 16);
            pk.y = bf16r(a[2]*inv) | (bf16r(a[3]*inv) << 16);
            *reinterpret_cast<uint2*>(smemB + qlocal*128 + ((ch ^ (qlocal & 7)) << 3) + (g & 1)*4) = pk;
        }
    }
    #pragma unroll
    for (int i = 0; i < 4; ++i) {               // stage wob[128][128] into smemA
        int id = tid + (i << 9);
        int r = id >> 4, c = id & 15;
        uint4 v = *reinterpret_cast<const uint4*>(wot + (size_t)r*DIM + c*8);
        *reinterpret_cast<uint4*>(smemA + r*128 + ((c ^ (r & 7)) << 3)) = v;
    }
    __syncthreads();

    // wo GEMM: D[32 rows][128 cols]; wave w owns cols w*16..+15
    f32x4 acc2[2] = {{0.f,0.f,0.f,0.f},{0.f,0.f,0.f,0.f}};
    #pragma unroll
    for (int ks = 0; ks < 4; ++ks) {
        int rb = w*16 + n;
        short8 bw = *reinterpret_cast<const short8*>(
            smemA + rb*128 + (((ks*4 + g) ^ (rb & 7)) << 3));
        #pragma unroll
        for (int mt = 0; mt < 2; ++mt) {
            int ra = mt*16 + n;
            short8 af = *reinterpret_cast<const short8*>(
                smemB + ra*128 + (((ks*4 + g) ^ (ra & 7)) << 3));
            acc2[mt] = __builtin_amdgcn_mfma_f32_16x16x32_bf16(af, bw, acc2[mt], 0, 0, 0);
        }
    }

    // epilogue: bias + residual + LN over the 32 rows
    const int col = w*16 + n;
    float vals[2][4];
    {
        float bv = bo[col];
        #pragma unroll
        for (int mt = 0; mt < 2; ++mt)
            #pragma unroll
            for (int r4 = 0; r4 < 4; ++r4) {
                int grow = qt*32 + mt*16 + g*4 + r4;
                float hres = (grow < TT) ? h[(size_t)(b*TT + grow)*DIM + col] : 0.f;
                vals[mt][r4] = acc2[mt][r4] + bv + hres;
            }
    }
    #pragma unroll
    for (int mt = 0; mt < 2; ++mt)
        #pragma unroll
        for (int r4 = 0; r4 < 4; ++r4) {
            float s = vals[mt][r4], s2 = vals[mt][r4]*vals[mt][r4];
            #pragma unroll
            for (int off = 1; off < 16; off <<= 1) {
                s  += __shfl_xor(s, off);
                s2 += __shfl_xor(s2, off);
            }
            if (n == 0) { red[w][mt*16 + g*4 + r4][0] = s; red[w][mt*16 + g*4 + r4][1] = s2; }
        }
    __syncthreads();
    if (tid < 32) {
        float s = 0.f, s2 = 0.f;
        #pragma unroll
        for (int ww = 0; ww < 8; ++ww) { s += red[ww][tid][0]; s2 += red[ww][tid][1]; }
        float mean = s * (1.f/128.f);
        float var  = s2 * (1.f/128.f) - mean*mean;
        stats[tid][0] = mean;
        stats[tid][1] = rsqrtf(var + 1e-5f);
    }
    __syncthreads();
    {
        float gv = lng[col], lb = lnb[col];
        #pragma unroll
        for (int mt = 0; mt < 2; ++mt)
            #pragma unroll
            for (int r4 = 0; r4 < 4; ++r4) {
                int rloc = mt*16 + g*4 + r4;
                int grow = qt*32 + rloc;
                if (grow < TT) {
                    float y = (vals[mt][r4] - stats[rloc][0]) * stats[rloc][1] * gv + lb;
                    size_t idx = (size_t)(b*TT + grow)*DIM + col;
                    h[idx]  = y;
                    hb[idx] = (ushort_t)bf16r(y);
                }
            }
    }
}

// ---------------- fully fused FFN: h = LN2(h + relu(hb@W1+b1)@W2 + b2) ----------------
__global__ __launch_bounds__(256) void ffn_kernel(
    const ushort_t* __restrict__ hbin, const ushort_t* __restrict__ W1t,
    const ushort_t* __restrict__ W2t, const float* __restrict__ b1v,
    const float* __restrict__ b2v, float* __restrict__ h, ushort_t* __restrict__ hb,
    const float* __restrict__ lng, const float* __restrict__ lnb)
{
    __shared__ __align__(16) ushort_t As[32 * 128];     // hb tile  (8 KB)
    __shared__ __align__(16) ushort_t Wbuf[128 * 128];  // weight chunk (32 KB)
    __shared__ __align__(16) ushort_t Mid[32 * 512];    // mid tile (32 KB)
    __shared__ float red[4][32][2];
    __shared__ float stats[32][2];
    const int tid = threadIdx.x;
    const int row0 = blockIdx.x << 5;
    const int w = tid >> 6, lane = tid & 63, g = lane >> 4, n = lane & 15;

    #pragma unroll
    for (int i = 0; i < 2; ++i) {
        int id = tid + 256*i;
        int r = id >> 4, c = id & 15;
        uint4 v = *reinterpret_cast<const uint4*>(hbin + (size_t)(row0 + r)*DIM + c*8);
        *reinterpret_cast<uint4*>(As + r*128 + ((c ^ (r & 7)) << 3)) = v;
    }

    for (int cc = 0; cc < 4; ++cc) {
        __syncthreads();
        #pragma unroll
        for (int i = 0; i < 8; ++i) {
            int id = tid + 256*i;
            int r = id >> 4, c = id & 15;
            uint4 v = *reinterpret_cast<const uint4*>(W1t + (size_t)(cc*128 + r)*DIM + c*8);
            *reinterpret_cast<uint4*>(Wbuf + r*128 + ((c ^ (r & 7)) << 3)) = v;
        }
        __syncthreads();
        f32x4 acc[2][2];
        #pragma unroll
        for (int a = 0; a < 2; ++a)
            #pragma unroll
            for (int b = 0; b < 2; ++b) acc[a][b] = (f32x4){0.f,0.f,0.f,0.f};
        #pragma unroll
        for (int ks = 0; ks < 4; ++ks) {
            short8 aw[2], bh[2];
            #pragma unroll
            for (int at = 0; at < 2; ++at) {
                int r = w*32 + at*16 + n;
                aw[at] = *reinterpret_cast<const short8*>(Wbuf + r*128 + (((ks*4 + g) ^ (r & 7)) << 3));
            }
            #pragma unroll
            for (int mt = 0; mt < 2; ++mt) {
                int r = mt*16 + n;
                bh[mt] = *reinterpret_cast<const short8*>(As + r*128 + (((ks*4 + g) ^ (r & 7)) << 3));
            }
            #pragma unroll
            for (int at = 0; at < 2; ++at)
                #pragma unroll
                for (int mt = 0; mt < 2; ++mt)
                    acc[at][mt] = __builtin_amdgcn_mfma_f32_16x16x32_bf16(aw[at], bh[mt], acc[at][mt], 0, 0, 0);
        }
        #pragma unroll
        for (int at = 0; at < 2; ++at) {
            int k1b = cc*128 + w*32 + at*16 + g*4;
            float4 bb = *reinterpret_cast<const float4*>(b1v + k1b);
            int ch = k1b >> 3;
            int halfoff = (g & 1) * 4;
            #pragma unroll
            for (int mt = 0; mt < 2; ++mt) {
                int mrow = mt*16 + n;
                float v0 = fmaxf(acc[at][mt][0] + bb.x, 0.f);
                float v1 = fmaxf(acc[at][mt][1] + bb.y, 0.f);
                float v2 = fmaxf(acc[at][mt][2] + bb.z, 0.f);
                float v3 = fmaxf(acc[at][mt][3] + bb.w, 0.f);
                uint2 pk;
                pk.x = bf16r(v0) | (bf16r(v1) << 16);
                pk.y = bf16r(v2) | (bf16r(v3) << 16);
                *reinterpret_cast<uint2*>(Mid + mrow*512 + ((ch ^ (mrow & 7)) << 3) + halfoff) = pk;
            }
        }
    }

    f32x4 oacc[2][2];
    #pragma unroll
    for (int a = 0; a < 2; ++a)
        #pragma unroll
        for (int b = 0; b < 2; ++b) oacc[a][b] = (f32x4){0.f,0.f,0.f,0.f};
    for (int kc = 0; kc < 4; ++kc) {
        __syncthreads();
        #pragma unroll
        for (int i = 0; i < 8; ++i) {
            int id = tid + 256*i;
            int r = id >> 4, c = id & 15;
            uint4 v = *reinterpret_cast<const uint4*>(W2t + (size_t)r*FFD + kc*128 + c*8);
            *reinterpret_cast<uint4*>(Wbuf + r*128 + ((c ^ (r & 7)) << 3)) = v;
        }
        __syncthreads();
        #pragma unroll
        for (int ks = 0; ks < 4; ++ks) {
            short8 aw[2], bm[2];
            #pragma unroll
            for (int ct = 0; ct < 2; ++ct) {
                int r = w*32 + ct*16 + n;
                aw[ct] = *reinterpret_cast<const short8*>(Wbuf + r*128 + (((ks*4 + g) ^ (r & 7)) << 3));
            }
            #pragma unroll
            for (int mt = 0; mt < 2; ++mt) {
                int r = mt*16 + n;
                int ch = kc*16 + ks*4 + g;
                bm[mt] = *reinterpret_cast<const short8*>(Mid + r*512 + ((ch ^ (r & 7)) << 3));
            }
            #pragma unroll
            for (int ct = 0; ct < 2; ++ct)
                #pragma unroll
                for (int mt = 0; mt < 2; ++mt)
                    oacc[ct][mt] = __builtin_amdgcn_mfma_f32_16x16x32_bf16(aw[ct], bm[mt], oacc[ct][mt], 0, 0, 0);
        }
    }

    float vals[2][2][4];
    #pragma unroll
    for (int ct = 0; ct < 2; ++ct) {
        int colb = w*32 + ct*16 + g*4;
        float4 bb = *reinterpret_cast<const float4*>(b2v + colb);
        #pragma unroll
        for (int mt = 0; mt < 2; ++mt) {
            int mrow = row0 + mt*16 + n;
            float4 hres = *reinterpret_cast<const float4*>(h + (size_t)mrow*DIM + colb);
            vals[ct][mt][0] = oacc[ct][mt][0] + bb.x + hres.x;
            vals[ct][mt][1] = oacc[ct][mt][1] + bb.y + hres.y;
            vals[ct][mt][2] = oacc[ct][mt][2] + bb.z + hres.z;
            vals[ct][mt][3] = oacc[ct][mt][3] + bb.w + hres.w;
        }
    }
    #pragma unroll
    for (int mt = 0; mt < 2; ++mt) {
        float s = 0.f, s2 = 0.f;
        #pragma unroll
        for (int ct = 0; ct < 2; ++ct)
            #pragma unroll
            for (int r4 = 0; r4 < 4; ++r4) { float v = vals[ct][mt][r4]; s += v; s2 += v*v; }
        s  += __shfl_xor(s, 16);  s  += __shfl_xor(s, 32);
        s2 += __shfl_xor(s2, 16); s2 += __shfl_xor(s2, 32);
        if (g == 0) { red[w][mt*16 + n][0] = s; red[w][mt*16 + n][1] = s2; }
    }
    __syncthreads();
    if (tid < 32) {
        float s = 0.f, s2 = 0.f;
        #pragma unroll
        for (int ww = 0; ww < 4; ++ww) { s += red[ww][tid][0]; s2 += red[ww][tid][1]; }
        float mean = s * (1.f/128.f);
        float var  = s2 * (1.f/128.f) - mean*mean;
        stats[tid][0] = mean;
        stats[tid][1] = rsqrtf(var + 1e-5f);
    }
    __syncthreads();
    #pragma unroll
    for (int ct = 0; ct < 2; ++ct) {
        int colb = w*32 + ct*16 + g*4;
        float4 gv = *reinterpret_cast<const float4*>(lng + colb);
        float4 bv = *reinterpret_cast<const float4*>(lnb + colb);
        #pragma unroll
        for (int mt = 0; mt < 2; ++mt) {
            int rloc = mt*16 + n;
            int mrow = row0 + rloc;
            float mean = stats[rloc][0], rstd = stats[rloc][1];
            float y0 = (vals[ct][mt][0] - mean) * rstd * gv.x + bv.x;
            float y1 = (vals[ct][mt][1] - mean) * rstd * gv.y + bv.y;
            float y2 = (vals[ct][mt][2] - mean) * rstd * gv.z + bv.z;
            float y3 = (vals[ct][mt][3] - mean) * rstd * gv.w + bv.w;
            float4 yo = {y0, y1, y2, y3};
            *reinterpret_cast<float4*>(h + (size_t)mrow*DIM + colb) = yo;
            uint2 pk;
            pk.x = bf16r(y0) | (bf16r(y1) << 16);
            pk.y = bf16r(y2) | (bf16r(y3) << 16);
            *reinterpret_cast<uint2*>(hb + (size_t)mrow*DIM + colb) = pk;
        }
    }
}

// ---------------- mean-pool + LN + classifier ----------------
__global__ __launch_bounds__(128) void final_kernel(
    const float* __restrict__ h, const float* __restrict__ g,
    const float* __restrict__ bt, const float* __restrict__ cls_w,
    const float* __restrict__ cls_b, float* __restrict__ out)
{
    int b = blockIdx.x, d = threadIdx.x;
    float s = 0.f;
    for (int t = 0; t < TT; ++t) s += h[((size_t)b*TT + t)*DIM + d];
    float pooled = s * (1.f / TT);
    __shared__ float sm[4];
    float v1 = pooled, v2 = pooled * pooled;
    #pragma unroll
    for (int off = 1; off < 64; off <<= 1) { v1 += __shfl_xor(v1, off); v2 += __shfl_xor(v2, off); }
    int wave = threadIdx.x >> 6, lane = threadIdx.x & 63;
    if (lane == 0) { sm[wave*2] = v1; sm[wave*2+1] = v2; }
    __syncthreads();
    float mean = (sm[0] + sm[2]) * (1.f/128.f);
    float var  = (sm[1] + sm[3]) * (1.f/128.f) - mean*mean;
    float xn = (pooled - mean) * rsqrtf(var + 1e-5f) * g[d] + bt[d];
    __shared__ float px[DIM];
    px[d] = xn;
    __syncthreads();
    if (d < NCLS_) {
        float a = cls_b[d];
        for (int i = 0; i < DIM; ++i) a = fmaf(px[i], cls_w[i*NCLS_ + d], a);
        out[b*NCLS_ + d] = a;
    }
}

// ---------------- host ----------------
extern "C" void kernel_launch(void* const* d_in, const int* in_sizes, int n_in,
                              void* d_out, int out_size, void* d_ws, size_t ws_size,
                              hipStream_t stream)
{
    (void)in_sizes; (void)n_in; (void)out_size; (void)ws_size;
    const float* x1      = (const float*)d_in[0];
    const float* proj_w  = (const float*)d_in[1];
    const float* proj_b  = (const float*)d_in[2];
    const float* queries = (const float*)d_in[3];
    const float* fc_w    = (const float*)d_in[4];
    const float* fc_b    = (const float*)d_in[5];
    const float* embed_w = (const float*)d_in[6];
    const float* embed_b = (const float*)d_in[7];
    const float* wqkv    = (const float*)d_in[8];
    const float* bqkv    = (const float*)d_in[9];
    const float* wo      = (const float*)d_in[10];
    const float* bo      = (const float*)d_in[11];
    const float* w1      = (const float*)d_in[12];
    const float* b1      = (const float*)d_in[13];
    const float* w2      = (const float*)d_in[14];
    const float* b2      = (const float*)d_in[15];
    const float* ln1_g   = (const float*)d_in[16];
    const float* ln1_b   = (const float*)d_in[17];
    const float* ln2_g   = (const float*)d_in[18];
    const float* ln2_b   = (const float*)d_in[19];
    const float* rel_t   = (const float*)d_in[20];
    const float* final_g = (const float*)d_in[21];
    const float* final_b = (const float*)d_in[22];
    const float* cls_w   = (const float*)d_in[23];
    const float* cls_b   = (const float*)d_in[24];

    float* ws     = (float*)d_ws;
    float* h      = ws;                                    // MM*128 f32
    ushort_t* hb    = (ushort_t*)(h + (size_t)MM*DIM);     // MM*128 bf16
    ushort_t* qkvb  = hb    + (size_t)MM*DIM;              // MM*384 bf16
    ushort_t* wts   = qkvb  + (size_t)MM*384;              // 1179648 bf16
    float* alpha  = (float*)(wts + 1179648);               // 16
    float* Emat   = alpha + 16;                            // 10*128
    float* c0     = Emat + QOUT_*DIM;                      // 128

    enc_pre_kernel<<<1, 128, 0, stream>>>(proj_w, proj_b, queries, fc_w, fc_b,
                                          embed_w, embed_b, alpha, Emat, c0);
    wtrans_kernel<<<288, 256, 0, stream>>>(wqkv, wo, w1, w2, wts);
    enc_kernel<<<MM, 64, 0, stream>>>(x1, alpha, Emat, c0, h, hb);

    for (int l = 0; l < NL; ++l) {
        const ushort_t* wqkv_t = wts + (size_t)l*49152;
        const ushort_t* wo_t   = wts + 294912 + (size_t)l*16384;
        const ushort_t* w1_t   = wts + 393216 + (size_t)l*65536;
        const ushort_t* w2_t   = wts + 786432 + (size_t)l*65536;

        gemm_mfma_kernel<128><<<dim3(384/64, MM/128), 256, 0, stream>>>(
            hb, wqkv_t, bqkv + l*3*DIM, qkvb, 384, DIM, 0, 1);
        attn_fused_kernel<<<BB*16, 512, 0, stream>>>(
            qkvb, rel_t + l*RELLEN, wo_t, bo + l*DIM, h, hb,
            ln1_g + l*DIM, ln1_b + l*DIM);
        ffn_kernel<<<MM/32, 256, 0, stream>>>(
            hb, w1_t, w2_t, b1 + l*FFD, b2 + l*DIM, h, hb,
            ln2_g + l*DIM, ln2_b + l*DIM);
    }

    final_kernel<<<BB, 128, 0, stream>>>(h, final_g, final_b, cls_w, cls_b, (float*)d_out);
}

// Round 7
// 412.503 us; speedup vs baseline: 1.0959x; 1.0959x over previous
//
#include <hip/hip_runtime.h>
#include <hip/hip_bf16.h>
#include <cmath>

#define NL      6
#define NHEADS  4
#define DIM     128
#define FFD     512
#define CMID_   8
#define COUT_   16
#define QOUT_   10
#define MAXLEN_ 512
#define NCLS_   3
#define BB      32
#define TT      500
#define FIN_    232
#define MM      (BB*TT)
#define HD      32
#define RELLEN  (2*MAXLEN_-1)
#define LOG2E   1.4426950408889634f

typedef __attribute__((ext_vector_type(8))) short short8;
typedef __attribute__((ext_vector_type(4))) float f32x4;
typedef unsigned short ushort_t;

__device__ inline unsigned bf16r(float x) {   // RNE float->bf16 bits (finite inputs)
    unsigned u = __float_as_uint(x);
    return (u + 0x7fffu + ((u >> 16) & 1u)) >> 16;
}

// paired RNE pack via HW v_cvt_pk_bf16_f32 (compiler lowers this cast)
__device__ inline unsigned pkbf16(float a, float b) {
    __hip_bfloat162 h2 = __float22bfloat162_rn(float2{a, b});
    return *reinterpret_cast<unsigned*>(&h2);
}

// ---------------- encoder precompute (1 block) ----------------
__global__ __launch_bounds__(128) void enc_pre_kernel(
    const float* __restrict__ proj_w, const float* __restrict__ proj_b,
    const float* __restrict__ queries, const float* __restrict__ fc_w,
    const float* __restrict__ fc_b, const float* __restrict__ embed_w,
    const float* __restrict__ embed_b,
    float* __restrict__ alpha, float* __restrict__ E, float* __restrict__ c0)
{
    __shared__ float pw[CMID_], cb[CMID_], gam[COUT_], del[COUT_];
    int t = threadIdx.x;
    if (t < CMID_) { pw[t] = proj_w[t]; cb[t] = proj_b[t] + ((t & 1) ? 1.f : 0.f); }
    __syncthreads();
    if (t < QOUT_) {
        float a = 0.f;
        for (int c = 0; c < CMID_; ++c) a += pw[c] * queries[t*CMID_ + c];
        alpha[t] = a;
    }
    if (t < COUT_) {
        float gg = 0.f, dd = 0.f;
        for (int c = 0; c < CMID_; ++c) {
            gg += pw[c] * fc_w[c*COUT_ + t];
            dd += cb[c] * fc_w[c*COUT_ + t];
        }
        gam[t] = gg; del[t] = dd + fc_b[t];
    }
    __syncthreads();
    for (int i = t; i < QOUT_*DIM; i += 128) {
        int q = i / DIM, d = i % DIM;
        float e = 0.f;
        for (int o = 0; o < COUT_; ++o) e += gam[o] * embed_w[(o*QOUT_ + q)*DIM + d];
        E[i] = e;
    }
    {
        float c = embed_b[t];
        for (int o = 0; o < COUT_; ++o) {
            float dl = del[o];
            for (int q = 0; q < QOUT_; ++q) c += dl * embed_w[(o*QOUT_ + q)*DIM + t];
        }
        c0[t] = c;
    }
}

// ---------------- encoder main ----------------
__global__ __launch_bounds__(64) void enc_kernel(
    const float* __restrict__ x1, const float* __restrict__ alpha,
    const float* __restrict__ E, const float* __restrict__ c0,
    float* __restrict__ h, ushort_t* __restrict__ hb)
{
    int bt = blockIdx.x;
    int lane = threadIdx.x;
    const float* xr = x1 + (size_t)bt * FIN_;
    float xv[4];
    bool vld[4];
    #pragma unroll
    for (int i = 0; i < 4; ++i) {
        int f = lane + (i << 6);
        vld[i] = (f < FIN_);
        xv[i] = vld[i] ? xr[f] : 0.f;
    }
    float vmax = -INFINITY, vmin = INFINITY;
    #pragma unroll
    for (int i = 0; i < 4; ++i) if (vld[i]) { vmax = fmaxf(vmax, xv[i]); vmin = fminf(vmin, xv[i]); }
    #pragma unroll
    for (int off = 1; off < 64; off <<= 1) {
        vmax = fmaxf(vmax, __shfl_xor(vmax, off));
        vmin = fminf(vmin, __shfl_xor(vmin, off));
    }
    float mq[QOUT_];
    for (int q = 0; q < QOUT_; ++q) {
        float a = alpha[q];
        float Mx = (a >= 0.f) ? a * vmax : a * vmin;
        float se = 0.f, sx = 0.f;
        #pragma unroll
        for (int i = 0; i < 4; ++i) if (vld[i]) {
            float e = __expf(fmaf(a, xv[i], -Mx));
            se += e; sx += e * xv[i];
        }
        #pragma unroll
        for (int off = 1; off < 64; off <<= 1) { se += __shfl_xor(se, off); sx += __shfl_xor(sx, off); }
        mq[q] = sx / se;
    }
    #pragma unroll
    for (int k = 0; k < 2; ++k) {
        int d = lane + (k << 6);
        float hv = c0[d];
        #pragma unroll
        for (int q = 0; q < QOUT_; ++q) hv = fmaf(mq[q], E[q*DIM + d], hv);
        h[(size_t)bt*DIM + d] = hv;
        hb[(size_t)bt*DIM + d] = (ushort_t)bf16r(hv);
    }
}

// ---------------- weight transpose + bf16 convert (once per launch) ----------------
__global__ __launch_bounds__(256) void wtrans_kernel(
    const float* __restrict__ wqkv, const float* __restrict__ wo,
    const float* __restrict__ w1, const float* __restrict__ w2,
    ushort_t* __restrict__ wts)
{
    int bid = blockIdx.x;
    const float* W; ushort_t* Wt; int K, N, tk, tn;
    if (bid < 72) {            // wqkv: K=128,N=384 -> 2x6 tiles x 6 layers
        int l = bid / 12, t = bid % 12; tk = t / 6; tn = t % 6; K = 128; N = 384;
        W = wqkv + (size_t)l*128*384; Wt = wts + (size_t)l*49152;
    } else if (bid < 96) {     // wo: 128x128 -> 2x2 x 6
        int q = bid - 72; int l = q / 4, t = q % 4; tk = t / 2; tn = t % 2; K = 128; N = 128;
        W = wo + (size_t)l*16384; Wt = wts + 294912 + (size_t)l*16384;
    } else if (bid < 192) {    // w1: K=128,N=512 -> 2x8 x 6
        int q = bid - 96; int l = q / 16, t = q % 16; tk = t / 8; tn = t % 8; K = 128; N = 512;
        W = w1 + (size_t)l*65536; Wt = wts + 393216 + (size_t)l*65536;
    } else {                   // w2: K=512,N=128 -> 8x2 x 6
        int q = bid - 192; int l = q / 16, t = q % 16; tk = t / 2; tn = t % 2; K = 512; N = 128;
        W = w2 + (size_t)l*65536; Wt = wts + 786432 + (size_t)l*65536;
    }
    int k0 = tk << 6, n0 = tn << 6;
    __shared__ float Ls[64][65];
    int tid = threadIdx.x;
    #pragma unroll
    for (int i = 0; i < 4; ++i) {
        int id = tid + 256*i;
        int r = id >> 4, ch = id & 15;
        float4 v = *reinterpret_cast<const float4*>(W + (size_t)(k0+r)*N + n0 + ch*4);
        Ls[ch*4+0][r] = v.x; Ls[ch*4+1][r] = v.y; Ls[ch*4+2][r] = v.z; Ls[ch*4+3][r] = v.w;
    }
    __syncthreads();
    #pragma unroll
    for (int i = 0; i < 4; ++i) {
        int id = tid + 256*i;
        int rr = id >> 4, ch = id & 15;
        uint2 o2;
        o2.x = pkbf16(Ls[rr][ch*4+0], Ls[rr][ch*4+1]);
        o2.y = pkbf16(Ls[rr][ch*4+2], Ls[rr][ch*4+3]);
        *reinterpret_cast<uint2*>(Wt + (size_t)(n0+rr)*K + k0 + ch*4) = o2;
    }
}

// ---------------- bf16 MFMA GEMM (qkv projection) ----------------
template<int BM>
__global__ __launch_bounds__(256) void gemm_mfma_kernel(
    const ushort_t* __restrict__ A, const ushort_t* __restrict__ Wt,
    const float* __restrict__ bias, void* __restrict__ C,
    int N, int K, int relu, int obf16)
{
    constexpr int MREP = BM / 32;
    constexpr int APT  = BM / 32;
    __shared__ __align__(16) ushort_t As[BM * 64];
    __shared__ __align__(16) ushort_t Bs[64 * 64];
    const int tid = threadIdx.x;
    const int row0 = blockIdx.y * BM, col0 = blockIdx.x << 6;
    const int w = tid >> 6, lane = tid & 63, g = lane >> 4, n = lane & 15;
    const int wr = w & 1, wc = w >> 1;
    f32x4 acc[MREP][2];
    #pragma unroll
    for (int mt = 0; mt < MREP; ++mt)
        #pragma unroll
        for (int nt = 0; nt < 2; ++nt) acc[mt][nt] = (f32x4){0.f,0.f,0.f,0.f};

    for (int k0 = 0; k0 < K; k0 += 64) {
        __syncthreads();
        #pragma unroll
        for (int i = 0; i < APT; ++i) {
            int id = tid + 256*i;
            int r = id >> 3, c = id & 7;
            uint4 v = *reinterpret_cast<const uint4*>(A + (size_t)(row0 + r)*K + k0 + c*8);
            *reinterpret_cast<uint4*>(As + r*64 + ((c ^ (r & 7)) << 3)) = v;
        }
        #pragma unroll
        for (int i = 0; i < 2; ++i) {
            int id = tid + 256*i;
            int r = id >> 3, c = id & 7;
            uint4 v = *reinterpret_cast<const uint4*>(Wt + (size_t)(col0 + r)*K + k0 + c*8);
            *reinterpret_cast<uint4*>(Bs + r*64 + ((c ^ (r & 7)) << 3)) = v;
        }
        __syncthreads();
        #pragma unroll
        for (int ks = 0; ks < 2; ++ks) {
            short8 af[MREP], bfr[2];
            #pragma unroll
            for (int mt = 0; mt < MREP; ++mt) {
                int r = wr*(BM/2) + mt*16 + n;
                af[mt] = *reinterpret_cast<const short8*>(As + r*64 + (((ks*4 + g) ^ (r & 7)) << 3));
            }
            #pragma unroll
            for (int nt = 0; nt < 2; ++nt) {
                int r = wc*32 + nt*16 + n;
                bfr[nt] = *reinterpret_cast<const short8*>(Bs + r*64 + (((ks*4 + g) ^ (r & 7)) << 3));
            }
            #pragma unroll
            for (int mt = 0; mt < MREP; ++mt)
                #pragma unroll
                for (int nt = 0; nt < 2; ++nt)
                    acc[mt][nt] = __builtin_amdgcn_mfma_f32_16x16x32_bf16(af[mt], bfr[nt], acc[mt][nt], 0, 0, 0);
        }
    }
    #pragma unroll
    for (int mt = 0; mt < MREP; ++mt) {
        #pragma unroll
        for (int nt = 0; nt < 2; ++nt) {
            int col = col0 + wc*32 + nt*16 + n;
            float bv = bias[col];
            #pragma unroll
            for (int r4 = 0; r4 < 4; ++r4) {
                int row = row0 + wr*(BM/2) + mt*16 + g*4 + r4;
                float v = acc[mt][nt][r4] + bv;
                if (relu) v = fmaxf(v, 0.f);
                if (obf16) ((ushort_t*)C)[(size_t)row*N + col] = (ushort_t)bf16r(v);
                else       ((float*)C)[(size_t)row*N + col] = v;
            }
        }
    }
}

// ---------------- fused GEMM + bias + residual + LayerNorm (wo path, K=128) -------
__global__ __launch_bounds__(256) void gemm_ln_kernel(
    const ushort_t* __restrict__ A, const ushort_t* __restrict__ Wt,
    const float* __restrict__ bias, float* __restrict__ h, ushort_t* __restrict__ hb,
    const float* __restrict__ lng, const float* __restrict__ lnb, int K)
{
    __shared__ __align__(16) ushort_t As[32 * 64];
    __shared__ __align__(16) ushort_t Bs[128 * 64];
    __shared__ float red[4][32][2];
    __shared__ float stats[32][2];
    const int tid = threadIdx.x;
    const int row0 = blockIdx.x << 5;
    const int wc = tid >> 6, lane = tid & 63, g = lane >> 4, n = lane & 15;
    f32x4 acc[2][2];
    #pragma unroll
    for (int mt = 0; mt < 2; ++mt)
        #pragma unroll
        for (int nt = 0; nt < 2; ++nt) acc[mt][nt] = (f32x4){0.f,0.f,0.f,0.f};

    for (int k0 = 0; k0 < K; k0 += 64) {
        __syncthreads();
        {
            int r = tid >> 3, c = tid & 7;
            uint4 v = *reinterpret_cast<const uint4*>(A + (size_t)(row0 + r)*K + k0 + c*8);
            *reinterpret_cast<uint4*>(As + r*64 + ((c ^ (r & 7)) << 3)) = v;
        }
        #pragma unroll
        for (int i = 0; i < 4; ++i) {
            int id = tid + 256*i;
            int r = id >> 3, c = id & 7;
            uint4 v = *reinterpret_cast<const uint4*>(Wt + (size_t)r*K + k0 + c*8);
            *reinterpret_cast<uint4*>(Bs + r*64 + ((c ^ (r & 7)) << 3)) = v;
        }
        __syncthreads();
        #pragma unroll
        for (int ks = 0; ks < 2; ++ks) {
            short8 af[2], bfr[2];
            #pragma unroll
            for (int mt = 0; mt < 2; ++mt) {
                int r = mt*16 + n;
                af[mt] = *reinterpret_cast<const short8*>(As + r*64 + (((ks*4 + g) ^ (r & 7)) << 3));
            }
            #pragma unroll
            for (int nt = 0; nt < 2; ++nt) {
                int r = wc*32 + nt*16 + n;
                bfr[nt] = *reinterpret_cast<const short8*>(Bs + r*64 + (((ks*4 + g) ^ (r & 7)) << 3));
            }
            #pragma unroll
            for (int mt = 0; mt < 2; ++mt)
                #pragma unroll
                for (int nt = 0; nt < 2; ++nt)
                    acc[mt][nt] = __builtin_amdgcn_mfma_f32_16x16x32_bf16(af[mt], bfr[nt], acc[mt][nt], 0, 0, 0);
        }
    }

    float vals[2][2][4];
    #pragma unroll
    for (int nt = 0; nt < 2; ++nt) {
        int col = wc*32 + nt*16 + n;
        float bv = bias[col];
        #pragma unroll
        for (int mt = 0; mt < 2; ++mt)
            #pragma unroll
            for (int r4 = 0; r4 < 4; ++r4) {
                int row = row0 + mt*16 + g*4 + r4;
                vals[mt][nt][r4] = acc[mt][nt][r4] + bv + h[(size_t)row*DIM + col];
            }
    }
    #pragma unroll
    for (int mt = 0; mt < 2; ++mt)
        #pragma unroll
        for (int r4 = 0; r4 < 4; ++r4) {
            float s  = vals[mt][0][r4] + vals[mt][1][r4];
            float s2 = vals[mt][0][r4]*vals[mt][0][r4] + vals[mt][1][r4]*vals[mt][1][r4];
            #pragma unroll
            for (int off = 1; off < 16; off <<= 1) {
                s  += __shfl_xor(s, off);
                s2 += __shfl_xor(s2, off);
            }
            if (n == 0) { red[wc][mt*16 + g*4 + r4][0] = s; red[wc][mt*16 + g*4 + r4][1] = s2; }
        }
    __syncthreads();
    if (tid < 32) {
        float s = 0.f, s2 = 0.f;
        #pragma unroll
        for (int ww = 0; ww < 4; ++ww) { s += red[ww][tid][0]; s2 += red[ww][tid][1]; }
        float mean = s * (1.f/128.f);
        float var  = s2 * (1.f/128.f) - mean*mean;
        stats[tid][0] = mean;
        stats[tid][1] = rsqrtf(var + 1e-5f);
    }
    __syncthreads();
    #pragma unroll
    for (int nt = 0; nt < 2; ++nt) {
        int col = wc*32 + nt*16 + n;
        float gv = lng[col], bv = lnb[col];
        #pragma unroll
        for (int mt = 0; mt < 2; ++mt)
            #pragma unroll
            for (int r4 = 0; r4 < 4; ++r4) {
                int rloc = mt*16 + g*4 + r4;
                int row = row0 + rloc;
                float y = (vals[mt][nt][r4] - stats[rloc][0]) * stats[rloc][1] * gv + bv;
                h[(size_t)row*DIM + col]  = y;
                hb[(size_t)row*DIM + col] = (ushort_t)bf16r(y);
            }
    }
}

// ---------------- fully fused FFN: h = LN2(h + relu(hb@W1+b1)@W2 + b2) ----------------
__global__ __launch_bounds__(256) void ffn_kernel(
    const ushort_t* __restrict__ hbin, const ushort_t* __restrict__ W1t,
    const ushort_t* __restrict__ W2t, const float* __restrict__ b1v,
    const float* __restrict__ b2v, float* __restrict__ h, ushort_t* __restrict__ hb,
    const float* __restrict__ lng, const float* __restrict__ lnb)
{
    __shared__ __align__(16) ushort_t As[32 * 128];     // hb tile  (8 KB)
    __shared__ __align__(16) ushort_t Wbuf[128 * 128];  // weight chunk (32 KB)
    __shared__ __align__(16) ushort_t Mid[32 * 512];    // mid tile (32 KB)
    __shared__ float red[4][32][2];
    __shared__ float stats[32][2];
    const int tid = threadIdx.x;
    const int row0 = blockIdx.x << 5;
    const int w = tid >> 6, lane = tid & 63, g = lane >> 4, n = lane & 15;

    #pragma unroll
    for (int i = 0; i < 2; ++i) {
        int id = tid + 256*i;
        int r = id >> 4, c = id & 15;
        uint4 v = *reinterpret_cast<const uint4*>(hbin + (size_t)(row0 + r)*DIM + c*8);
        *reinterpret_cast<uint4*>(As + r*128 + ((c ^ (r & 7)) << 3)) = v;
    }

    for (int cc = 0; cc < 4; ++cc) {
        __syncthreads();
        #pragma unroll
        for (int i = 0; i < 8; ++i) {
            int id = tid + 256*i;
            int r = id >> 4, c = id & 15;
            uint4 v = *reinterpret_cast<const uint4*>(W1t + (size_t)(cc*128 + r)*DIM + c*8);
            *reinterpret_cast<uint4*>(Wbuf + r*128 + ((c ^ (r & 7)) << 3)) = v;
        }
        __syncthreads();
        f32x4 acc[2][2];
        #pragma unroll
        for (int a = 0; a < 2; ++a)
            #pragma unroll
            for (int b = 0; b < 2; ++b) acc[a][b] = (f32x4){0.f,0.f,0.f,0.f};
        #pragma unroll
        for (int ks = 0; ks < 4; ++ks) {
            short8 aw[2], bh[2];
            #pragma unroll
            for (int at = 0; at < 2; ++at) {
                int r = w*32 + at*16 + n;
                aw[at] = *reinterpret_cast<const short8*>(Wbuf + r*128 + (((ks*4 + g) ^ (r & 7)) << 3));
            }
            #pragma unroll
            for (int mt = 0; mt < 2; ++mt) {
                int r = mt*16 + n;
                bh[mt] = *reinterpret_cast<const short8*>(As + r*128 + (((ks*4 + g) ^ (r & 7)) << 3));
            }
            #pragma unroll
            for (int at = 0; at < 2; ++at)
                #pragma unroll
                for (int mt = 0; mt < 2; ++mt)
                    acc[at][mt] = __builtin_amdgcn_mfma_f32_16x16x32_bf16(aw[at], bh[mt], acc[at][mt], 0, 0, 0);
        }
        #pragma unroll
        for (int at = 0; at < 2; ++at) {
            int k1b = cc*128 + w*32 + at*16 + g*4;
            float4 bb = *reinterpret_cast<const float4*>(b1v + k1b);
            int ch = k1b >> 3;
            int halfoff = (g & 1) * 4;
            #pragma unroll
            for (int mt = 0; mt < 2; ++mt) {
                int mrow = mt*16 + n;
                float v0 = fmaxf(acc[at][mt][0] + bb.x, 0.f);
                float v1 = fmaxf(acc[at][mt][1] + bb.y, 0.f);
                float v2 = fmaxf(acc[at][mt][2] + bb.z, 0.f);
                float v3 = fmaxf(acc[at][mt][3] + bb.w, 0.f);
                uint2 pk;
                pk.x = pkbf16(v0, v1);
                pk.y = pkbf16(v2, v3);
                *reinterpret_cast<uint2*>(Mid + mrow*512 + ((ch ^ (mrow & 7)) << 3) + halfoff) = pk;
            }
        }
    }

    f32x4 oacc[2][2];
    #pragma unroll
    for (int a = 0; a < 2; ++a)
        #pragma unroll
        for (int b = 0; b < 2; ++b) oacc[a][b] = (f32x4){0.f,0.f,0.f,0.f};
    for (int kc = 0; kc < 4; ++kc) {
        __syncthreads();
        #pragma unroll
        for (int i = 0; i < 8; ++i) {
            int id = tid + 256*i;
            int r = id >> 4, c = id & 15;
            uint4 v = *reinterpret_cast<const uint4*>(W2t + (size_t)r*FFD + kc*128 + c*8);
            *reinterpret_cast<uint4*>(Wbuf + r*128 + ((c ^ (r & 7)) << 3)) = v;
        }
        __syncthreads();
        #pragma unroll
        for (int ks = 0; ks < 4; ++ks) {
            short8 aw[2], bm[2];
            #pragma unroll
            for (int ct = 0; ct < 2; ++ct) {
                int r = w*32 + ct*16 + n;
                aw[ct] = *reinterpret_cast<const short8*>(Wbuf + r*128 + (((ks*4 + g) ^ (r & 7)) << 3));
            }
            #pragma unroll
            for (int mt = 0; mt < 2; ++mt) {
                int r = mt*16 + n;
                int ch = kc*16 + ks*4 + g;
                bm[mt] = *reinterpret_cast<const short8*>(Mid + r*512 + ((ch ^ (r & 7)) << 3));
            }
            #pragma unroll
            for (int ct = 0; ct < 2; ++ct)
                #pragma unroll
                for (int mt = 0; mt < 2; ++mt)
                    oacc[ct][mt] = __builtin_amdgcn_mfma_f32_16x16x32_bf16(aw[ct], bm[mt], oacc[ct][mt], 0, 0, 0);
        }
    }

    float vals[2][2][4];
    #pragma unroll
    for (int ct = 0; ct < 2; ++ct) {
        int colb = w*32 + ct*16 + g*4;
        float4 bb = *reinterpret_cast<const float4*>(b2v + colb);
        #pragma unroll
        for (int mt = 0; mt < 2; ++mt) {
            int mrow = row0 + mt*16 + n;
            float4 hres = *reinterpret_cast<const float4*>(h + (size_t)mrow*DIM + colb);
            vals[ct][mt][0] = oacc[ct][mt][0] + bb.x + hres.x;
            vals[ct][mt][1] = oacc[ct][mt][1] + bb.y + hres.y;
            vals[ct][mt][2] = oacc[ct][mt][2] + bb.z + hres.z;
            vals[ct][mt][3] = oacc[ct][mt][3] + bb.w + hres.w;
        }
    }
    #pragma unroll
    for (int mt = 0; mt < 2; ++mt) {
        float s = 0.f, s2 = 0.f;
        #pragma unroll
        for (int ct = 0; ct < 2; ++ct)
            #pragma unroll
            for (int r4 = 0; r4 < 4; ++r4) { float v = vals[ct][mt][r4]; s += v; s2 += v*v; }
        s  += __shfl_xor(s, 16);  s  += __shfl_xor(s, 32);
        s2 += __shfl_xor(s2, 16); s2 += __shfl_xor(s2, 32);
        if (g == 0) { red[w][mt*16 + n][0] = s; red[w][mt*16 + n][1] = s2; }
    }
    __syncthreads();
    if (tid < 32) {
        float s = 0.f, s2 = 0.f;
        #pragma unroll
        for (int ww = 0; ww < 4; ++ww) { s += red[ww][tid][0]; s2 += red[ww][tid][1]; }
        float mean = s * (1.f/128.f);
        float var  = s2 * (1.f/128.f) - mean*mean;
        stats[tid][0] = mean;
        stats[tid][1] = rsqrtf(var + 1e-5f);
    }
    __syncthreads();
    #pragma unroll
    for (int ct = 0; ct < 2; ++ct) {
        int colb = w*32 + ct*16 + g*4;
        float4 gv = *reinterpret_cast<const float4*>(lng + colb);
        float4 bv = *reinterpret_cast<const float4*>(lnb + colb);
        #pragma unroll
        for (int mt = 0; mt < 2; ++mt) {
            int rloc = mt*16 + n;
            int mrow = row0 + rloc;
            float mean = stats[rloc][0], rstd = stats[rloc][1];
            float y0 = (vals[ct][mt][0] - mean) * rstd * gv.x + bv.x;
            float y1 = (vals[ct][mt][1] - mean) * rstd * gv.y + bv.y;
            float y2 = (vals[ct][mt][2] - mean) * rstd * gv.z + bv.z;
            float y3 = (vals[ct][mt][3] - mean) * rstd * gv.w + bv.w;
            float4 yo = {y0, y1, y2, y3};
            *reinterpret_cast<float4*>(h + (size_t)mrow*DIM + colb) = yo;
            uint2 pk;
            pk.x = pkbf16(y0, y1);
            pk.y = pkbf16(y2, y3);
            *reinterpret_cast<uint2*>(hb + (size_t)mrow*DIM + colb) = pk;
        }
    }
}

// ---------------- MFMA bf16 flash attention (KVBLK=64, exp2 domain) ----------------
// grid: B*NHEADS*8 blocks, 256 threads = 4 waves x 16 q-rows each.
__global__ __launch_bounds__(256) void attn_mfma_kernel(
    const ushort_t* __restrict__ qkv, const float* __restrict__ rel,
    ushort_t* __restrict__ o)
{
    __shared__ __align__(16) ushort_t Ks[64][40];          // [kcol][dim] 80B rows
    __shared__ __align__(16) ushort_t Vs[64][36];          // [kcol][dim] 72B rows
    __shared__ __align__(16) ushort_t VB[2][2][4][16][8];  // [kchalf][dimhalf][g][n][j]
    __shared__ float rl[RELLEN];
    const int bid = blockIdx.x;
    const int qt = bid & 7;
    const int bh = bid >> 3;
    const int hh = bh & 3, b = bh >> 2;
    const int tid  = threadIdx.x;
    const int wq   = tid >> 6;
    const int lane = tid & 63;
    const int g = lane >> 4, n = lane & 15;
    for (int i = tid; i < RELLEN; i += 256) rl[i] = rel[i] * LOG2E;  // log2 domain

    const int qrow = (qt << 6) + (wq << 4) + n;
    const bool qv = (qrow < TT);
    short8 qf = {0,0,0,0,0,0,0,0};
    if (qv) qf = *reinterpret_cast<const short8*>(qkv + (size_t)(b*TT + qrow)*384 + hh*HD + g*8);

    f32x4 acc0 = {0.f,0.f,0.f,0.f}, acc1 = {0.f,0.f,0.f,0.f};
    float m = -INFINITY, lsum = 0.f;
    const float scale2 = 0.17677669529663687f * LOG2E;   // (1/sqrt(32))*log2e
    const f32x4 zf = {0.f,0.f,0.f,0.f};

    const int sr = tid >> 2, sc = tid & 3;      // stage: 64 rows x 4 chunks

    auto tile = [&](const int kt, const bool domask) {
        const int k0 = kt << 6;
        __syncthreads();                        // prev tile fully consumed
        {
            int t = k0 + sr;
            uint4 kvv = make_uint4(0,0,0,0), vvv = make_uint4(0,0,0,0);
            if (!domask || t < TT) {
                const ushort_t* bp = qkv + (size_t)(b*TT + t)*384 + hh*HD + sc*8;
                kvv = *reinterpret_cast<const uint4*>(bp + 128);
                vvv = *reinterpret_cast<const uint4*>(bp + 256);
            }
            *reinterpret_cast<uint4*>(&Ks[sr][sc*8]) = kvv;
            *reinterpret_cast<uint2*>(&Vs[sr][sc*8])     = make_uint2(vvv.x, vvv.y);
            *reinterpret_cast<uint2*>(&Vs[sr][sc*8 + 4]) = make_uint2(vvv.z, vvv.w);
        }
        __syncthreads();

        // V relayout into fragment-linear VB (concurrent with QK^T+softmax)
        {
            int kch = tid >> 7, dh = (tid >> 6) & 1, gg = (tid >> 4) & 3, nn = tid & 15;
            ushort_t tmp[8];
            #pragma unroll
            for (int j = 0; j < 8; ++j) tmp[j] = Vs[kch*32 + gg*8 + j][dh*16 + nn];
            *reinterpret_cast<uint4*>(&VB[kch][dh][gg][nn][0]) = *reinterpret_cast<uint4*>(tmp);
        }

        // S^T = K . Q^T : 4 tiles of 16 kcols
        f32x4 s[4];
        #pragma unroll
        for (int c = 0; c < 4; ++c) {
            short8 ak = *reinterpret_cast<const short8*>(&Ks[c*16 + n][g*8]);
            s[c] = __builtin_amdgcn_mfma_f32_16x16x32_bf16(ak, qf, zf, 0, 0, 0);
        }

        float sv[16];
        float tmax = -INFINITY;
        #pragma unroll
        for (int c = 0; c < 4; ++c)
            #pragma unroll
            for (int r = 0; r < 4; ++r) {
                int kc = k0 + c*16 + g*4 + r;
                float bia = rl[kc - qrow + (MAXLEN_-1)];
                float v = fmaf(s[c][r], scale2, bia);
                if (domask && kc >= TT) v = -1e30f;
                sv[c*4 + r] = v;
                tmax = fmaxf(tmax, v);
            }
        tmax = fmaxf(tmax, __shfl_xor(tmax, 16));
        tmax = fmaxf(tmax, __shfl_xor(tmax, 32));
        float mnew = fmaxf(m, tmax);
        float corr = exp2f(m - mnew);
        m = mnew;
        float ps = 0.f;
        #pragma unroll
        for (int r = 0; r < 16; ++r) { float e = exp2f(sv[r] - mnew); sv[r] = e; ps += e; }
        ps += __shfl_xor(ps, 16);
        ps += __shfl_xor(ps, 32);
        lsum = fmaf(lsum, corr, ps);

        int src0 = n + ((g & 1) << 5);
        int src1 = src0 + 16;
        int t0 = (g < 2);
        union { unsigned wd[4]; short8 v; } PA, PB;
        {
            unsigned pk0lo = pkbf16(sv[0], sv[1]);
            unsigned pk0hi = pkbf16(sv[2], sv[3]);
            unsigned pk1lo = pkbf16(sv[4], sv[5]);
            unsigned pk1hi = pkbf16(sv[6], sv[7]);
            unsigned a0 = __shfl((int)pk0lo, src0), c0_ = __shfl((int)pk1lo, src0);
            unsigned a1 = __shfl((int)pk0hi, src0), c1_ = __shfl((int)pk1hi, src0);
            unsigned a2 = __shfl((int)pk0lo, src1), c2_ = __shfl((int)pk1lo, src1);
            unsigned a3 = __shfl((int)pk0hi, src1), c3_ = __shfl((int)pk1hi, src1);
            PA.wd[0] = t0 ? a0 : c0_; PA.wd[1] = t0 ? a1 : c1_;
            PA.wd[2] = t0 ? a2 : c2_; PA.wd[3] = t0 ? a3 : c3_;
        }
        {
            unsigned pk0lo = pkbf16(sv[8],  sv[9]);
            unsigned pk0hi = pkbf16(sv[10], sv[11]);
            unsigned pk1lo = pkbf16(sv[12], sv[13]);
            unsigned pk1hi = pkbf16(sv[14], sv[15]);
            unsigned a0 = __shfl((int)pk0lo, src0), c0_ = __shfl((int)pk1lo, src0);
            unsigned a1 = __shfl((int)pk0hi, src0), c1_ = __shfl((int)pk1hi, src0);
            unsigned a2 = __shfl((int)pk0lo, src1), c2_ = __shfl((int)pk1lo, src1);
            unsigned a3 = __shfl((int)pk0hi, src1), c3_ = __shfl((int)pk1hi, src1);
            PB.wd[0] = t0 ? a0 : c0_; PB.wd[1] = t0 ? a1 : c1_;
            PB.wd[2] = t0 ? a2 : c2_; PB.wd[3] = t0 ? a3 : c3_;
        }

        __syncthreads();                        // VB ready
        short8 a00 = *reinterpret_cast<const short8*>(&VB[0][0][g][n][0]);
        short8 a01 = *reinterpret_cast<const short8*>(&VB[0][1][g][n][0]);
        short8 a10 = *reinterpret_cast<const short8*>(&VB[1][0][g][n][0]);
        short8 a11 = *reinterpret_cast<const short8*>(&VB[1][1][g][n][0]);
        #pragma unroll
        for (int r = 0; r < 4; ++r) { acc0[r] *= corr; acc1[r] *= corr; }
        acc0 = __builtin_amdgcn_mfma_f32_16x16x32_bf16(a00, PA.v, acc0, 0, 0, 0);
        acc0 = __builtin_amdgcn_mfma_f32_16x16x32_bf16(a10, PB.v, acc0, 0, 0, 0);
        acc1 = __builtin_amdgcn_mfma_f32_16x16x32_bf16(a01, PA.v, acc1, 0, 0, 0);
        acc1 = __builtin_amdgcn_mfma_f32_16x16x32_bf16(a11, PB.v, acc1, 0, 0, 0);
    };

    for (int kt = 0; kt < 7; ++kt) tile(kt, false);   // kcols 0..447 < 500: no mask
    tile(7, true);                                    // kcols 448..511: masked

    if (qv) {
        float inv = 1.f / lsum;
        uint2 p0, p1;
        p0.x = pkbf16(acc0[0]*inv, acc0[1]*inv);
        p0.y = pkbf16(acc0[2]*inv, acc0[3]*inv);
        p1.x = pkbf16(acc1[0]*inv, acc1[1]*inv);
        p1.y = pkbf16(acc1[2]*inv, acc1[3]*inv);
        ushort_t* op = o + (size_t)(b*TT + qrow)*DIM + hh*HD + g*4;
        *reinterpret_cast<uint2*>(op)      = p0;
        *reinterpret_cast<uint2*>(op + 16) = p1;
    }
}

// ---------------- mean-pool + LN + classifier ----------------
__global__ __launch_bounds__(128) void final_kernel(
    const float* __restrict__ h, const float* __restrict__ g,
    const float* __restrict__ bt, const float* __restrict__ cls_w,
    const float* __restrict__ cls_b, float* __restrict__ out)
{
    int b = blockIdx.x, d = threadIdx.x;
    float s = 0.f;
    for (int t = 0; t < TT; ++t) s += h[((size_t)b*TT + t)*DIM + d];
    float pooled = s * (1.f / TT);
    __shared__ float sm[4];
    float v1 = pooled, v2 = pooled * pooled;
    #pragma unroll
    for (int off = 1; off < 64; off <<= 1) { v1 += __shfl_xor(v1, off); v2 += __shfl_xor(v2, off); }
    int wave = threadIdx.x >> 6, lane = threadIdx.x & 63;
    if (lane == 0) { sm[wave*2] = v1; sm[wave*2+1] = v2; }
    __syncthreads();
    float mean = (sm[0] + sm[2]) * (1.f/128.f);
    float var  = (sm[1] + sm[3]) * (1.f/128.f) - mean*mean;
    float xn = (pooled - mean) * rsqrtf(var + 1e-5f) * g[d] + bt[d];
    __shared__ float px[DIM];
    px[d] = xn;
    __syncthreads();
    if (d < NCLS_) {
        float a = cls_b[d];
        for (int i = 0; i < DIM; ++i) a = fmaf(px[i], cls_w[i*NCLS_ + d], a);
        out[b*NCLS_ + d] = a;
    }
}

// ---------------- host ----------------
extern "C" void kernel_launch(void* const* d_in, const int* in_sizes, int n_in,
                              void* d_out, int out_size, void* d_ws, size_t ws_size,
                              hipStream_t stream)
{
    (void)in_sizes; (void)n_in; (void)out_size; (void)ws_size;
    const float* x1      = (const float*)d_in[0];
    const float* proj_w  = (const float*)d_in[1];
    const float* proj_b  = (const float*)d_in[2];
    const float* queries = (const float*)d_in[3];
    const float* fc_w    = (const float*)d_in[4];
    const float* fc_b    = (const float*)d_in[5];
    const float* embed_w = (const float*)d_in[6];
    const float* embed_b = (const float*)d_in[7];
    const float* wqkv    = (const float*)d_in[8];
    const float* bqkv    = (const float*)d_in[9];
    const float* wo      = (const float*)d_in[10];
    const float* bo      = (const float*)d_in[11];
    const float* w1      = (const float*)d_in[12];
    const float* b1      = (const float*)d_in[13];
    const float* w2      = (const float*)d_in[14];
    const float* b2      = (const float*)d_in[15];
    const float* ln1_g   = (const float*)d_in[16];
    const float* ln1_b   = (const float*)d_in[17];
    const float* ln2_g   = (const float*)d_in[18];
    const float* ln2_b   = (const float*)d_in[19];
    const float* rel_t   = (const float*)d_in[20];
    const float* final_g = (const float*)d_in[21];
    const float* final_b = (const float*)d_in[22];
    const float* cls_w   = (const float*)d_in[23];
    const float* cls_b   = (const float*)d_in[24];

    float* ws     = (float*)d_ws;
    float* h      = ws;                                    // MM*128 f32
    ushort_t* hb    = (ushort_t*)(h + (size_t)MM*DIM);     // MM*128 bf16
    ushort_t* qkvb  = hb    + (size_t)MM*DIM;              // MM*384 bf16
    ushort_t* attno = qkvb  + (size_t)MM*384;              // MM*128 bf16
    ushort_t* wts   = attno + (size_t)MM*DIM;              // 1179648 bf16
    float* alpha  = (float*)(wts + 1179648);               // 16
    float* Emat   = alpha + 16;                            // 10*128
    float* c0     = Emat + QOUT_*DIM;                      // 128

    enc_pre_kernel<<<1, 128, 0, stream>>>(proj_w, proj_b, queries, fc_w, fc_b,
                                          embed_w, embed_b, alpha, Emat, c0);
    wtrans_kernel<<<288, 256, 0, stream>>>(wqkv, wo, w1, w2, wts);
    enc_kernel<<<MM, 64, 0, stream>>>(x1, alpha, Emat, c0, h, hb);

    for (int l = 0; l < NL; ++l) {
        const ushort_t* wqkv_t = wts + (size_t)l*49152;
        const ushort_t* wo_t   = wts + 294912 + (size_t)l*16384;
        const ushort_t* w1_t   = wts + 393216 + (size_t)l*65536;
        const ushort_t* w2_t   = wts + 786432 + (size_t)l*65536;

        gemm_mfma_kernel<128><<<dim3(384/64, MM/128), 256, 0, stream>>>(
            hb, wqkv_t, bqkv + l*3*DIM, qkvb, 384, DIM, 0, 1);
        attn_mfma_kernel<<<BB*NHEADS*8, 256, 0, stream>>>(
            qkvb, rel_t + l*RELLEN, attno);
        gemm_ln_kernel<<<MM/32, 256, 0, stream>>>(
            attno, wo_t, bo + l*DIM, h, hb, ln1_g + l*DIM, ln1_b + l*DIM, DIM);
        ffn_kernel<<<MM/32, 256, 0, stream>>>(
            hb, w1_t, w2_t, b1 + l*FFD, b2 + l*DIM, h, hb,
            ln2_g + l*DIM, ln2_b + l*DIM);
    }

    final_kernel<<<BB, 128, 0, stream>>>(h, final_g, final_b, cls_w, cls_b, (float*)d_out);
}

// Round 8
// 407.513 us; speedup vs baseline: 1.1094x; 1.0122x over previous
//
#include <hip/hip_runtime.h>
#include <hip/hip_bf16.h>
#include <cmath>

#define NL      6
#define NHEADS  4
#define DIM     128
#define FFD     512
#define CMID_   8
#define COUT_   16
#define QOUT_   10
#define MAXLEN_ 512
#define NCLS_   3
#define BB      32
#define TT      500
#define FIN_    232
#define MM      (BB*TT)
#define HD      32
#define RELLEN  (2*MAXLEN_-1)
#define LOG2E   1.4426950408889634f

typedef __attribute__((ext_vector_type(8))) short short8;
typedef __attribute__((ext_vector_type(4))) float f32x4;
typedef unsigned short ushort_t;

__device__ inline unsigned bf16r(float x) {   // RNE float->bf16 bits (finite inputs)
    unsigned u = __float_as_uint(x);
    return (u + 0x7fffu + ((u >> 16) & 1u)) >> 16;
}

// paired RNE pack via HW v_cvt_pk_bf16_f32
__device__ inline unsigned pkbf16(float a, float b) {
    __hip_bfloat162 h2 = __float22bfloat162_rn(float2{a, b});
    return *reinterpret_cast<unsigned*>(&h2);
}

// ---------------- encoder precompute (1 block) ----------------
__global__ __launch_bounds__(128) void enc_pre_kernel(
    const float* __restrict__ proj_w, const float* __restrict__ proj_b,
    const float* __restrict__ queries, const float* __restrict__ fc_w,
    const float* __restrict__ fc_b, const float* __restrict__ embed_w,
    const float* __restrict__ embed_b,
    float* __restrict__ alpha, float* __restrict__ E, float* __restrict__ c0)
{
    __shared__ float pw[CMID_], cb[CMID_], gam[COUT_], del[COUT_];
    int t = threadIdx.x;
    if (t < CMID_) { pw[t] = proj_w[t]; cb[t] = proj_b[t] + ((t & 1) ? 1.f : 0.f); }
    __syncthreads();
    if (t < QOUT_) {
        float a = 0.f;
        for (int c = 0; c < CMID_; ++c) a += pw[c] * queries[t*CMID_ + c];
        alpha[t] = a;
    }
    if (t < COUT_) {
        float gg = 0.f, dd = 0.f;
        for (int c = 0; c < CMID_; ++c) {
            gg += pw[c] * fc_w[c*COUT_ + t];
            dd += cb[c] * fc_w[c*COUT_ + t];
        }
        gam[t] = gg; del[t] = dd + fc_b[t];
    }
    __syncthreads();
    for (int i = t; i < QOUT_*DIM; i += 128) {
        int q = i / DIM, d = i % DIM;
        float e = 0.f;
        for (int o = 0; o < COUT_; ++o) e += gam[o] * embed_w[(o*QOUT_ + q)*DIM + d];
        E[i] = e;
    }
    {
        float c = embed_b[t];
        for (int o = 0; o < COUT_; ++o) {
            float dl = del[o];
            for (int q = 0; q < QOUT_; ++q) c += dl * embed_w[(o*QOUT_ + q)*DIM + t];
        }
        c0[t] = c;
    }
}

// ---------------- encoder main ----------------
__global__ __launch_bounds__(64) void enc_kernel(
    const float* __restrict__ x1, const float* __restrict__ alpha,
    const float* __restrict__ E, const float* __restrict__ c0,
    float* __restrict__ h, ushort_t* __restrict__ hb)
{
    int bt = blockIdx.x;
    int lane = threadIdx.x;
    const float* xr = x1 + (size_t)bt * FIN_;
    float xv[4];
    bool vld[4];
    #pragma unroll
    for (int i = 0; i < 4; ++i) {
        int f = lane + (i << 6);
        vld[i] = (f < FIN_);
        xv[i] = vld[i] ? xr[f] : 0.f;
    }
    float vmax = -INFINITY, vmin = INFINITY;
    #pragma unroll
    for (int i = 0; i < 4; ++i) if (vld[i]) { vmax = fmaxf(vmax, xv[i]); vmin = fminf(vmin, xv[i]); }
    #pragma unroll
    for (int off = 1; off < 64; off <<= 1) {
        vmax = fmaxf(vmax, __shfl_xor(vmax, off));
        vmin = fminf(vmin, __shfl_xor(vmin, off));
    }
    float mq[QOUT_];
    for (int q = 0; q < QOUT_; ++q) {
        float a = alpha[q];
        float Mx = (a >= 0.f) ? a * vmax : a * vmin;
        float se = 0.f, sx = 0.f;
        #pragma unroll
        for (int i = 0; i < 4; ++i) if (vld[i]) {
            float e = __expf(fmaf(a, xv[i], -Mx));
            se += e; sx += e * xv[i];
        }
        #pragma unroll
        for (int off = 1; off < 64; off <<= 1) { se += __shfl_xor(se, off); sx += __shfl_xor(sx, off); }
        mq[q] = sx / se;
    }
    #pragma unroll
    for (int k = 0; k < 2; ++k) {
        int d = lane + (k << 6);
        float hv = c0[d];
        #pragma unroll
        for (int q = 0; q < QOUT_; ++q) hv = fmaf(mq[q], E[q*DIM + d], hv);
        h[(size_t)bt*DIM + d] = hv;
        hb[(size_t)bt*DIM + d] = (ushort_t)bf16r(hv);
    }
}

// ---------------- weight transpose + bf16 convert (once per launch) ----------------
__global__ __launch_bounds__(256) void wtrans_kernel(
    const float* __restrict__ wqkv, const float* __restrict__ wo,
    const float* __restrict__ w1, const float* __restrict__ w2,
    ushort_t* __restrict__ wts)
{
    int bid = blockIdx.x;
    const float* W; ushort_t* Wt; int K, N, tk, tn;
    if (bid < 72) {            // wqkv: K=128,N=384 -> 2x6 tiles x 6 layers
        int l = bid / 12, t = bid % 12; tk = t / 6; tn = t % 6; K = 128; N = 384;
        W = wqkv + (size_t)l*128*384; Wt = wts + (size_t)l*49152;
    } else if (bid < 96) {     // wo: 128x128 -> 2x2 x 6
        int q = bid - 72; int l = q / 4, t = q % 4; tk = t / 2; tn = t % 2; K = 128; N = 128;
        W = wo + (size_t)l*16384; Wt = wts + 294912 + (size_t)l*16384;
    } else if (bid < 192) {    // w1: K=128,N=512 -> 2x8 x 6
        int q = bid - 96; int l = q / 16, t = q % 16; tk = t / 8; tn = t % 8; K = 128; N = 512;
        W = w1 + (size_t)l*65536; Wt = wts + 393216 + (size_t)l*65536;
    } else {                   // w2: K=512,N=128 -> 8x2 x 6
        int q = bid - 192; int l = q / 16, t = q % 16; tk = t / 2; tn = t % 2; K = 512; N = 128;
        W = w2 + (size_t)l*65536; Wt = wts + 786432 + (size_t)l*65536;
    }
    int k0 = tk << 6, n0 = tn << 6;
    __shared__ float Ls[64][65];
    int tid = threadIdx.x;
    #pragma unroll
    for (int i = 0; i < 4; ++i) {
        int id = tid + 256*i;
        int r = id >> 4, ch = id & 15;
        float4 v = *reinterpret_cast<const float4*>(W + (size_t)(k0+r)*N + n0 + ch*4);
        Ls[ch*4+0][r] = v.x; Ls[ch*4+1][r] = v.y; Ls[ch*4+2][r] = v.z; Ls[ch*4+3][r] = v.w;
    }
    __syncthreads();
    #pragma unroll
    for (int i = 0; i < 4; ++i) {
        int id = tid + 256*i;
        int rr = id >> 4, ch = id & 15;
        uint2 o2;
        o2.x = pkbf16(Ls[rr][ch*4+0], Ls[rr][ch*4+1]);
        o2.y = pkbf16(Ls[rr][ch*4+2], Ls[rr][ch*4+3]);
        *reinterpret_cast<uint2*>(Wt + (size_t)(n0+rr)*K + k0 + ch*4) = o2;
    }
}

// ---------------- bf16 MFMA GEMM (qkv projection) ----------------
template<int BM>
__global__ __launch_bounds__(256) void gemm_mfma_kernel(
    const ushort_t* __restrict__ A, const ushort_t* __restrict__ Wt,
    const float* __restrict__ bias, void* __restrict__ C,
    int N, int K, int relu, int obf16)
{
    constexpr int MREP = BM / 32;
    constexpr int APT  = BM / 32;
    __shared__ __align__(16) ushort_t As[BM * 64];
    __shared__ __align__(16) ushort_t Bs[64 * 64];
    const int tid = threadIdx.x;
    const int row0 = blockIdx.y * BM, col0 = blockIdx.x << 6;
    const int w = tid >> 6, lane = tid & 63, g = lane >> 4, n = lane & 15;
    const int wr = w & 1, wc = w >> 1;
    f32x4 acc[MREP][2];
    #pragma unroll
    for (int mt = 0; mt < MREP; ++mt)
        #pragma unroll
        for (int nt = 0; nt < 2; ++nt) acc[mt][nt] = (f32x4){0.f,0.f,0.f,0.f};

    for (int k0 = 0; k0 < K; k0 += 64) {
        __syncthreads();
        #pragma unroll
        for (int i = 0; i < APT; ++i) {
            int id = tid + 256*i;
            int r = id >> 3, c = id & 7;
            uint4 v = *reinterpret_cast<const uint4*>(A + (size_t)(row0 + r)*K + k0 + c*8);
            *reinterpret_cast<uint4*>(As + r*64 + ((c ^ (r & 7)) << 3)) = v;
        }
        #pragma unroll
        for (int i = 0; i < 2; ++i) {
            int id = tid + 256*i;
            int r = id >> 3, c = id & 7;
            uint4 v = *reinterpret_cast<const uint4*>(Wt + (size_t)(col0 + r)*K + k0 + c*8);
            *reinterpret_cast<uint4*>(Bs + r*64 + ((c ^ (r & 7)) << 3)) = v;
        }
        __syncthreads();
        #pragma unroll
        for (int ks = 0; ks < 2; ++ks) {
            short8 af[MREP], bfr[2];
            #pragma unroll
            for (int mt = 0; mt < MREP; ++mt) {
                int r = wr*(BM/2) + mt*16 + n;
                af[mt] = *reinterpret_cast<const short8*>(As + r*64 + (((ks*4 + g) ^ (r & 7)) << 3));
            }
            #pragma unroll
            for (int nt = 0; nt < 2; ++nt) {
                int r = wc*32 + nt*16 + n;
                bfr[nt] = *reinterpret_cast<const short8*>(Bs + r*64 + (((ks*4 + g) ^ (r & 7)) << 3));
            }
            #pragma unroll
            for (int mt = 0; mt < MREP; ++mt)
                #pragma unroll
                for (int nt = 0; nt < 2; ++nt)
                    acc[mt][nt] = __builtin_amdgcn_mfma_f32_16x16x32_bf16(af[mt], bfr[nt], acc[mt][nt], 0, 0, 0);
        }
    }
    #pragma unroll
    for (int mt = 0; mt < MREP; ++mt) {
        #pragma unroll
        for (int nt = 0; nt < 2; ++nt) {
            int col = col0 + wc*32 + nt*16 + n;
            float bv = bias[col];
            #pragma unroll
            for (int r4 = 0; r4 < 4; ++r4) {
                int row = row0 + wr*(BM/2) + mt*16 + g*4 + r4;
                float v = acc[mt][nt][r4] + bv;
                if (relu) v = fmaxf(v, 0.f);
                if (obf16) ((ushort_t*)C)[(size_t)row*N + col] = (ushort_t)bf16r(v);
                else       ((float*)C)[(size_t)row*N + col] = v;
            }
        }
    }
}

// ---------------- MFMA bf16 flash attention (QBLK=128, KVBLK=64, exp2) ----------------
// grid: B*NHEADS*4 blocks, 512 threads = 8 waves x 16 q-rows each; K/V staged once
// per tile serve all 128 q-rows.
__global__ __launch_bounds__(512) void attn_mfma_kernel(
    const ushort_t* __restrict__ qkv, const float* __restrict__ rel,
    ushort_t* __restrict__ o)
{
    __shared__ __align__(16) ushort_t Ks[64][40];          // [kcol][dim] 80B rows
    __shared__ __align__(16) ushort_t Vs[64][36];          // [kcol][dim] 72B rows
    __shared__ __align__(16) ushort_t VB[2][2][4][16][8];  // [kchalf][dimhalf][g][n][j]
    __shared__ float rl[RELLEN];
    const int bid = blockIdx.x;
    const int qt = bid & 3;
    const int bh = bid >> 2;
    const int hh = bh & 3, b = bh >> 2;
    const int tid  = threadIdx.x;
    const int w    = tid >> 6;
    const int lane = tid & 63;
    const int g = lane >> 4, n = lane & 15;
    for (int i = tid; i < RELLEN; i += 512) rl[i] = rel[i] * LOG2E;

    const int qrow = (qt << 7) + (w << 4) + n;
    const bool qv = (qrow < TT);
    short8 qf = {0,0,0,0,0,0,0,0};
    if (qv) qf = *reinterpret_cast<const short8*>(qkv + (size_t)(b*TT + qrow)*384 + hh*HD + g*8);

    f32x4 acc0 = {0.f,0.f,0.f,0.f}, acc1 = {0.f,0.f,0.f,0.f};
    float m = -INFINITY, lsum = 0.f;
    const float scale2 = 0.17677669529663687f * LOG2E;
    const f32x4 zf = {0.f,0.f,0.f,0.f};

    const int sr = tid >> 3, sc = tid & 7;      // stage: 64 rows x 8 chunks of 8B

    auto tile = [&](const int kt, const bool domask) {
        const int k0 = kt << 6;
        __syncthreads();                        // prev tile fully consumed
        {
            int t = k0 + sr;
            uint2 kvv = make_uint2(0,0), vvv = make_uint2(0,0);
            if (!domask || t < TT) {
                const ushort_t* bp = qkv + (size_t)(b*TT + t)*384 + hh*HD + sc*4;
                kvv = *reinterpret_cast<const uint2*>(bp + 128);
                vvv = *reinterpret_cast<const uint2*>(bp + 256);
            }
            *reinterpret_cast<uint2*>(&Ks[sr][sc*4]) = kvv;
            *reinterpret_cast<uint2*>(&Vs[sr][sc*4]) = vvv;
        }
        __syncthreads();

        // V relayout into fragment-linear VB (4 elems/thread, 512 threads)
        {
            int jh = (tid & 1)*4, nn = (tid >> 1) & 15, gg = (tid >> 5) & 3;
            int dh = (tid >> 7) & 1, kch = (tid >> 8) & 1;
            ushort_t tmp[4];
            #pragma unroll
            for (int j = 0; j < 4; ++j) tmp[j] = Vs[kch*32 + gg*8 + jh + j][dh*16 + nn];
            *reinterpret_cast<uint2*>(&VB[kch][dh][gg][nn][jh]) = *reinterpret_cast<uint2*>(tmp);
        }

        // S^T = K . Q^T : 4 tiles of 16 kcols (per wave)
        f32x4 s[4];
        #pragma unroll
        for (int c = 0; c < 4; ++c) {
            short8 ak = *reinterpret_cast<const short8*>(&Ks[c*16 + n][g*8]);
            s[c] = __builtin_amdgcn_mfma_f32_16x16x32_bf16(ak, qf, zf, 0, 0, 0);
        }

        float sv[16];
        float tmax = -INFINITY;
        #pragma unroll
        for (int c = 0; c < 4; ++c)
            #pragma unroll
            for (int r = 0; r < 4; ++r) {
                int kc = k0 + c*16 + g*4 + r;
                float bia = rl[kc - qrow + (MAXLEN_-1)];
                float v = fmaf(s[c][r], scale2, bia);
                if (domask && kc >= TT) v = -1e30f;
                sv[c*4 + r] = v;
                tmax = fmaxf(tmax, v);
            }
        tmax = fmaxf(tmax, __shfl_xor(tmax, 16));
        tmax = fmaxf(tmax, __shfl_xor(tmax, 32));
        float mnew = fmaxf(m, tmax);
        float corr = exp2f(m - mnew);
        m = mnew;
        float ps = 0.f;
        #pragma unroll
        for (int r = 0; r < 16; ++r) { float e = exp2f(sv[r] - mnew); sv[r] = e; ps += e; }
        ps += __shfl_xor(ps, 16);
        ps += __shfl_xor(ps, 32);
        lsum = fmaf(lsum, corr, ps);

        int src0 = n + ((g & 1) << 5);
        int src1 = src0 + 16;
        int t0 = (g < 2);
        union { unsigned wd[4]; short8 v; } PA, PB;
        {
            unsigned pk0lo = pkbf16(sv[0], sv[1]);
            unsigned pk0hi = pkbf16(sv[2], sv[3]);
            unsigned pk1lo = pkbf16(sv[4], sv[5]);
            unsigned pk1hi = pkbf16(sv[6], sv[7]);
            unsigned a0 = __shfl((int)pk0lo, src0), c0_ = __shfl((int)pk1lo, src0);
            unsigned a1 = __shfl((int)pk0hi, src0), c1_ = __shfl((int)pk1hi, src0);
            unsigned a2 = __shfl((int)pk0lo, src1), c2_ = __shfl((int)pk1lo, src1);
            unsigned a3 = __shfl((int)pk0hi, src1), c3_ = __shfl((int)pk1hi, src1);
            PA.wd[0] = t0 ? a0 : c0_; PA.wd[1] = t0 ? a1 : c1_;
            PA.wd[2] = t0 ? a2 : c2_; PA.wd[3] = t0 ? a3 : c3_;
        }
        {
            unsigned pk0lo = pkbf16(sv[8],  sv[9]);
            unsigned pk0hi = pkbf16(sv[10], sv[11]);
            unsigned pk1lo = pkbf16(sv[12], sv[13]);
            unsigned pk1hi = pkbf16(sv[14], sv[15]);
            unsigned a0 = __shfl((int)pk0lo, src0), c0_ = __shfl((int)pk1lo, src0);
            unsigned a1 = __shfl((int)pk0hi, src0), c1_ = __shfl((int)pk1hi, src0);
            unsigned a2 = __shfl((int)pk0lo, src1), c2_ = __shfl((int)pk1lo, src1);
            unsigned a3 = __shfl((int)pk0hi, src1), c3_ = __shfl((int)pk1hi, src1);
            PB.wd[0] = t0 ? a0 : c0_; PB.wd[1] = t0 ? a1 : c1_;
            PB.wd[2] = t0 ? a2 : c2_; PB.wd[3] = t0 ? a3 : c3_;
        }

        __syncthreads();                        // VB ready
        short8 a00 = *reinterpret_cast<const short8*>(&VB[0][0][g][n][0]);
        short8 a01 = *reinterpret_cast<const short8*>(&VB[0][1][g][n][0]);
        short8 a10 = *reinterpret_cast<const short8*>(&VB[1][0][g][n][0]);
        short8 a11 = *reinterpret_cast<const short8*>(&VB[1][1][g][n][0]);
        #pragma unroll
        for (int r = 0; r < 4; ++r) { acc0[r] *= corr; acc1[r] *= corr; }
        acc0 = __builtin_amdgcn_mfma_f32_16x16x32_bf16(a00, PA.v, acc0, 0, 0, 0);
        acc0 = __builtin_amdgcn_mfma_f32_16x16x32_bf16(a10, PB.v, acc0, 0, 0, 0);
        acc1 = __builtin_amdgcn_mfma_f32_16x16x32_bf16(a01, PA.v, acc1, 0, 0, 0);
        acc1 = __builtin_amdgcn_mfma_f32_16x16x32_bf16(a11, PB.v, acc1, 0, 0, 0);
    };

    for (int kt = 0; kt < 7; ++kt) tile(kt, false);   // kcols 0..447 < 500
    tile(7, true);                                    // kcols 448..511 masked

    if (qv) {
        float inv = 1.f / lsum;
        uint2 p0, p1;
        p0.x = pkbf16(acc0[0]*inv, acc0[1]*inv);
        p0.y = pkbf16(acc0[2]*inv, acc0[3]*inv);
        p1.x = pkbf16(acc1[0]*inv, acc1[1]*inv);
        p1.y = pkbf16(acc1[2]*inv, acc1[3]*inv);
        ushort_t* op = o + (size_t)(b*TT + qrow)*DIM + hh*HD + g*4;
        *reinterpret_cast<uint2*>(op)      = p0;
        *reinterpret_cast<uint2*>(op + 16) = p1;
    }
}

// ---------------- fused post-attention: wo GEMM + LN1 + FFN + LN2 ----------------
// Per 32-row block: phaseA: C=attno@wo+bo+h -> LN1 -> y (f32 in Hres LDS, bf16 in As LDS);
// phaseB: Mid=relu(As@W1+b1) -> out=Mid@W2+b2+Hres -> LN2 -> h,hb global.
__global__ __launch_bounds__(256) void pa_kernel(
    const ushort_t* __restrict__ attno, const ushort_t* __restrict__ wot,
    const float* __restrict__ bo, const ushort_t* __restrict__ W1t,
    const ushort_t* __restrict__ W2t, const float* __restrict__ b1v,
    const float* __restrict__ b2v, float* __restrict__ h, ushort_t* __restrict__ hb,
    const float* __restrict__ ln1g, const float* __restrict__ ln1b,
    const float* __restrict__ ln2g, const float* __restrict__ ln2b)
{
    __shared__ __align__(16) ushort_t As[32 * 128];     // 8 KB: attno tile, then LN1 bf16
    __shared__ __align__(16) ushort_t Wbuf[8192];       // 16 KB weight chunk
    __shared__ __align__(16) ushort_t Mid[32 * 512];    // 32 KB
    __shared__ float Hres[32 * 132];                    // 16.9 KB, padded rows
    __shared__ float red[4][32][2];
    __shared__ float stats[32][2];
    const int tid = threadIdx.x;
    const int row0 = blockIdx.x << 5;
    const int w = tid >> 6, lane = tid & 63, g = lane >> 4, n = lane & 15;

    // stage attno tile (32 x 128)
    #pragma unroll
    for (int i = 0; i < 2; ++i) {
        int id = tid + 256*i;
        int r = id >> 4, c = id & 15;
        uint4 v = *reinterpret_cast<const uint4*>(attno + (size_t)(row0 + r)*DIM + c*8);
        *reinterpret_cast<uint4*>(As + r*128 + ((c ^ (r & 7)) << 3)) = v;
    }

    // ---- phase A: wo GEMM (K=128) ----
    f32x4 acc[2][2];
    #pragma unroll
    for (int a = 0; a < 2; ++a)
        #pragma unroll
        for (int b = 0; b < 2; ++b) acc[a][b] = (f32x4){0.f,0.f,0.f,0.f};
    #pragma unroll
    for (int k0 = 0; k0 < 128; k0 += 64) {
        __syncthreads();
        #pragma unroll
        for (int i = 0; i < 4; ++i) {          // Wbuf[128 n][64 k]
            int id = tid + 256*i;
            int r = id >> 3, c = id & 7;
            uint4 v = *reinterpret_cast<const uint4*>(wot + (size_t)r*DIM + k0 + c*8);
            *reinterpret_cast<uint4*>(Wbuf + r*64 + ((c ^ (r & 7)) << 3)) = v;
        }
        __syncthreads();
        #pragma unroll
        for (int ks = 0; ks < 2; ++ks) {
            short8 af[2], bfr[2];
            #pragma unroll
            for (int mt = 0; mt < 2; ++mt) {
                int r = mt*16 + n;
                int ch = (k0 >> 3) + ks*4 + g;
                af[mt] = *reinterpret_cast<const short8*>(As + r*128 + ((ch ^ (r & 7)) << 3));
            }
            #pragma unroll
            for (int nt = 0; nt < 2; ++nt) {
                int r = w*32 + nt*16 + n;
                bfr[nt] = *reinterpret_cast<const short8*>(Wbuf + r*64 + (((ks*4 + g) ^ (r & 7)) << 3));
            }
            #pragma unroll
            for (int mt = 0; mt < 2; ++mt)
                #pragma unroll
                for (int nt = 0; nt < 2; ++nt)
                    acc[mt][nt] = __builtin_amdgcn_mfma_f32_16x16x32_bf16(af[mt], bfr[nt], acc[mt][nt], 0, 0, 0);
        }
    }
    // epilogue A: bias + residual + LN1 -> Hres (f32) + As (bf16)
    {
        float vals[2][2][4];
        #pragma unroll
        for (int nt = 0; nt < 2; ++nt) {
            int col = w*32 + nt*16 + n;
            float bv = bo[col];
            #pragma unroll
            for (int mt = 0; mt < 2; ++mt)
                #pragma unroll
                for (int r4 = 0; r4 < 4; ++r4) {
                    int row = row0 + mt*16 + g*4 + r4;
                    vals[mt][nt][r4] = acc[mt][nt][r4] + bv + h[(size_t)row*DIM + col];
                }
        }
        #pragma unroll
        for (int mt = 0; mt < 2; ++mt)
            #pragma unroll
            for (int r4 = 0; r4 < 4; ++r4) {
                float s  = vals[mt][0][r4] + vals[mt][1][r4];
                float s2 = vals[mt][0][r4]*vals[mt][0][r4] + vals[mt][1][r4]*vals[mt][1][r4];
                #pragma unroll
                for (int off = 1; off < 16; off <<= 1) {
                    s  += __shfl_xor(s, off);
                    s2 += __shfl_xor(s2, off);
                }
                if (n == 0) { red[w][mt*16 + g*4 + r4][0] = s; red[w][mt*16 + g*4 + r4][1] = s2; }
            }
        __syncthreads();
        if (tid < 32) {
            float s = 0.f, s2 = 0.f;
            #pragma unroll
            for (int ww = 0; ww < 4; ++ww) { s += red[ww][tid][0]; s2 += red[ww][tid][1]; }
            float mean = s * (1.f/128.f);
            float var  = s2 * (1.f/128.f) - mean*mean;
            stats[tid][0] = mean;
            stats[tid][1] = rsqrtf(var + 1e-5f);
        }
        __syncthreads();
        #pragma unroll
        for (int nt = 0; nt < 2; ++nt) {
            int col = w*32 + nt*16 + n;
            int ch = col >> 3, off8 = col & 7;
            float gv = ln1g[col], bv = ln1b[col];
            #pragma unroll
            for (int mt = 0; mt < 2; ++mt)
                #pragma unroll
                for (int r4 = 0; r4 < 4; ++r4) {
                    int rloc = mt*16 + g*4 + r4;
                    float y = (vals[mt][nt][r4] - stats[rloc][0]) * stats[rloc][1] * gv + bv;
                    Hres[rloc*132 + col] = y;
                    As[rloc*128 + ((ch ^ (rloc & 7)) << 3) + off8] = (ushort_t)bf16r(y);
                }
        }
    }

    // ---- phase B1: Mid = relu(As @ W1 + b1), 8 chunks of 64 k1-cols ----
    for (int cc = 0; cc < 8; ++cc) {
        __syncthreads();
        #pragma unroll
        for (int i = 0; i < 4; ++i) {          // Wbuf[64 k1][128 k]
            int id = tid + 256*i;
            int r = id >> 4, c = id & 15;
            uint4 v = *reinterpret_cast<const uint4*>(W1t + (size_t)(cc*64 + r)*DIM + c*8);
            *reinterpret_cast<uint4*>(Wbuf + r*128 + ((c ^ (r & 7)) << 3)) = v;
        }
        __syncthreads();
        f32x4 acc1[2] = {{0.f,0.f,0.f,0.f},{0.f,0.f,0.f,0.f}};
        #pragma unroll
        for (int ks = 0; ks < 4; ++ks) {
            int rW = w*16 + n;
            short8 aw = *reinterpret_cast<const short8*>(Wbuf + rW*128 + (((ks*4 + g) ^ (rW & 7)) << 3));
            #pragma unroll
            for (int mt = 0; mt < 2; ++mt) {
                int rA = mt*16 + n;
                short8 bh_ = *reinterpret_cast<const short8*>(As + rA*128 + (((ks*4 + g) ^ (rA & 7)) << 3));
                acc1[mt] = __builtin_amdgcn_mfma_f32_16x16x32_bf16(aw, bh_, acc1[mt], 0, 0, 0);
            }
        }
        {
            int k1b = cc*64 + w*16 + g*4;
            float4 bb = *reinterpret_cast<const float4*>(b1v + k1b);
            int ch = k1b >> 3;
            int halfoff = (g & 1) * 4;
            #pragma unroll
            for (int mt = 0; mt < 2; ++mt) {
                int mrow = mt*16 + n;
                float v0 = fmaxf(acc1[mt][0] + bb.x, 0.f);
                float v1 = fmaxf(acc1[mt][1] + bb.y, 0.f);
                float v2 = fmaxf(acc1[mt][2] + bb.z, 0.f);
                float v3 = fmaxf(acc1[mt][3] + bb.w, 0.f);
                uint2 pk;
                pk.x = pkbf16(v0, v1);
                pk.y = pkbf16(v2, v3);
                *reinterpret_cast<uint2*>(Mid + mrow*512 + ((ch ^ (mrow & 7)) << 3) + halfoff) = pk;
            }
        }
    }

    // ---- phase B2: out = Mid @ W2, 8 chunks of 64 k1 ----
    f32x4 oacc[2][2];
    #pragma unroll
    for (int a = 0; a < 2; ++a)
        #pragma unroll
        for (int b = 0; b < 2; ++b) oacc[a][b] = (f32x4){0.f,0.f,0.f,0.f};
    for (int kc = 0; kc < 8; ++kc) {
        __syncthreads();
        #pragma unroll
        for (int i = 0; i < 4; ++i) {          // Wbuf[128 c][64 k1]
            int id = tid + 256*i;
            int r = id >> 3, c = id & 7;
            uint4 v = *reinterpret_cast<const uint4*>(W2t + (size_t)r*FFD + kc*64 + c*8);
            *reinterpret_cast<uint4*>(Wbuf + r*64 + ((c ^ (r & 7)) << 3)) = v;
        }
        __syncthreads();
        #pragma unroll
        for (int ks = 0; ks < 2; ++ks) {
            short8 aw[2], bm[2];
            #pragma unroll
            for (int ct = 0; ct < 2; ++ct) {
                int r = w*32 + ct*16 + n;
                aw[ct] = *reinterpret_cast<const short8*>(Wbuf + r*64 + (((ks*4 + g) ^ (r & 7)) << 3));
            }
            #pragma unroll
            for (int mt = 0; mt < 2; ++mt) {
                int r = mt*16 + n;
                int ch = kc*8 + ks*4 + g;
                bm[mt] = *reinterpret_cast<const short8*>(Mid + r*512 + ((ch ^ (r & 7)) << 3));
            }
            #pragma unroll
            for (int ct = 0; ct < 2; ++ct)
                #pragma unroll
                for (int mt = 0; mt < 2; ++mt)
                    oacc[ct][mt] = __builtin_amdgcn_mfma_f32_16x16x32_bf16(aw[ct], bm[mt], oacc[ct][mt], 0, 0, 0);
        }
    }

    // epilogue B: bias + residual(Hres) + LN2 -> h, hb
    float vals[2][2][4];
    #pragma unroll
    for (int ct = 0; ct < 2; ++ct) {
        int colb = w*32 + ct*16 + g*4;
        float4 bb = *reinterpret_cast<const float4*>(b2v + colb);
        #pragma unroll
        for (int mt = 0; mt < 2; ++mt) {
            int rloc = mt*16 + n;
            float4 hres = *reinterpret_cast<const float4*>(&Hres[rloc*132 + colb]);
            vals[ct][mt][0] = oacc[ct][mt][0] + bb.x + hres.x;
            vals[ct][mt][1] = oacc[ct][mt][1] + bb.y + hres.y;
            vals[ct][mt][2] = oacc[ct][mt][2] + bb.z + hres.z;
            vals[ct][mt][3] = oacc[ct][mt][3] + bb.w + hres.w;
        }
    }
    __syncthreads();                           // red[] reuse safe
    #pragma unroll
    for (int mt = 0; mt < 2; ++mt) {
        float s = 0.f, s2 = 0.f;
        #pragma unroll
        for (int ct = 0; ct < 2; ++ct)
            #pragma unroll
            for (int r4 = 0; r4 < 4; ++r4) { float v = vals[ct][mt][r4]; s += v; s2 += v*v; }
        s  += __shfl_xor(s, 16);  s  += __shfl_xor(s, 32);
        s2 += __shfl_xor(s2, 16); s2 += __shfl_xor(s2, 32);
        if (g == 0) { red[w][mt*16 + n][0] = s; red[w][mt*16 + n][1] = s2; }
    }
    __syncthreads();
    if (tid < 32) {
        float s = 0.f, s2 = 0.f;
        #pragma unroll
        for (int ww = 0; ww < 4; ++ww) { s += red[ww][tid][0]; s2 += red[ww][tid][1]; }
        float mean = s * (1.f/128.f);
        float var  = s2 * (1.f/128.f) - mean*mean;
        stats[tid][0] = mean;
        stats[tid][1] = rsqrtf(var + 1e-5f);
    }
    __syncthreads();
    #pragma unroll
    for (int ct = 0; ct < 2; ++ct) {
        int colb = w*32 + ct*16 + g*4;
        float4 gv = *reinterpret_cast<const float4*>(ln2g + colb);
        float4 bv = *reinterpret_cast<const float4*>(ln2b + colb);
        #pragma unroll
        for (int mt = 0; mt < 2; ++mt) {
            int rloc = mt*16 + n;
            int mrow = row0 + rloc;
            float mean = stats[rloc][0], rstd = stats[rloc][1];
            float y0 = (vals[ct][mt][0] - mean) * rstd * gv.x + bv.x;
            float y1 = (vals[ct][mt][1] - mean) * rstd * gv.y + bv.y;
            float y2 = (vals[ct][mt][2] - mean) * rstd * gv.z + bv.z;
            float y3 = (vals[ct][mt][3] - mean) * rstd * gv.w + bv.w;
            float4 yo = {y0, y1, y2, y3};
            *reinterpret_cast<float4*>(h + (size_t)mrow*DIM + colb) = yo;
            uint2 pk;
            pk.x = pkbf16(y0, y1);
            pk.y = pkbf16(y2, y3);
            *reinterpret_cast<uint2*>(hb + (size_t)mrow*DIM + colb) = pk;
        }
    }
}

// ---------------- mean-pool + LN + classifier ----------------
__global__ __launch_bounds__(128) void final_kernel(
    const float* __restrict__ h, const float* __restrict__ g,
    const float* __restrict__ bt, const float* __restrict__ cls_w,
    const float* __restrict__ cls_b, float* __restrict__ out)
{
    int b = blockIdx.x, d = threadIdx.x;
    float s = 0.f;
    for (int t = 0; t < TT; ++t) s += h[((size_t)b*TT + t)*DIM + d];
    float pooled = s * (1.f / TT);
    __shared__ float sm[4];
    float v1 = pooled, v2 = pooled * pooled;
    #pragma unroll
    for (int off = 1; off < 64; off <<= 1) { v1 += __shfl_xor(v1, off); v2 += __shfl_xor(v2, off); }
    int wave = threadIdx.x >> 6, lane = threadIdx.x & 63;
    if (lane == 0) { sm[wave*2] = v1; sm[wave*2+1] = v2; }
    __syncthreads();
    float mean = (sm[0] + sm[2]) * (1.f/128.f);
    float var  = (sm[1] + sm[3]) * (1.f/128.f) - mean*mean;
    float xn = (pooled - mean) * rsqrtf(var + 1e-5f) * g[d] + bt[d];
    __shared__ float px[DIM];
    px[d] = xn;
    __syncthreads();
    if (d < NCLS_) {
        float a = cls_b[d];
        for (int i = 0; i < DIM; ++i) a = fmaf(px[i], cls_w[i*NCLS_ + d], a);
        out[b*NCLS_ + d] = a;
    }
}

// ---------------- host ----------------
extern "C" void kernel_launch(void* const* d_in, const int* in_sizes, int n_in,
                              void* d_out, int out_size, void* d_ws, size_t ws_size,
                              hipStream_t stream)
{
    (void)in_sizes; (void)n_in; (void)out_size; (void)ws_size;
    const float* x1      = (const float*)d_in[0];
    const float* proj_w  = (const float*)d_in[1];
    const float* proj_b  = (const float*)d_in[2];
    const float* queries = (const float*)d_in[3];
    const float* fc_w    = (const float*)d_in[4];
    const float* fc_b    = (const float*)d_in[5];
    const float* embed_w = (const float*)d_in[6];
    const float* embed_b = (const float*)d_in[7];
    const float* wqkv    = (const float*)d_in[8];
    const float* bqkv    = (const float*)d_in[9];
    const float* wo      = (const float*)d_in[10];
    const float* bo      = (const float*)d_in[11];
    const float* w1      = (const float*)d_in[12];
    const float* b1      = (const float*)d_in[13];
    const float* w2      = (const float*)d_in[14];
    const float* b2      = (const float*)d_in[15];
    const float* ln1_g   = (const float*)d_in[16];
    const float* ln1_b   = (const float*)d_in[17];
    const float* ln2_g   = (const float*)d_in[18];
    const float* ln2_b   = (const float*)d_in[19];
    const float* rel_t   = (const float*)d_in[20];
    const float* final_g = (const float*)d_in[21];
    const float* final_b = (const float*)d_in[22];
    const float* cls_w   = (const float*)d_in[23];
    const float* cls_b   = (const float*)d_in[24];

    float* ws     = (float*)d_ws;
    float* h      = ws;                                    // MM*128 f32
    ushort_t* hb    = (ushort_t*)(h + (size_t)MM*DIM);     // MM*128 bf16
    ushort_t* qkvb  = hb    + (size_t)MM*DIM;              // MM*384 bf16
    ushort_t* attno = qkvb  + (size_t)MM*384;              // MM*128 bf16
    ushort_t* wts   = attno + (size_t)MM*DIM;              // 1179648 bf16
    float* alpha  = (float*)(wts + 1179648);               // 16
    float* Emat   = alpha + 16;                            // 10*128
    float* c0     = Emat + QOUT_*DIM;                      // 128

    enc_pre_kernel<<<1, 128, 0, stream>>>(proj_w, proj_b, queries, fc_w, fc_b,
                                          embed_w, embed_b, alpha, Emat, c0);
    wtrans_kernel<<<288, 256, 0, stream>>>(wqkv, wo, w1, w2, wts);
    enc_kernel<<<MM, 64, 0, stream>>>(x1, alpha, Emat, c0, h, hb);

    for (int l = 0; l < NL; ++l) {
        const ushort_t* wqkv_t = wts + (size_t)l*49152;
        const ushort_t* wo_t   = wts + 294912 + (size_t)l*16384;
        const ushort_t* w1_t   = wts + 393216 + (size_t)l*65536;
        const ushort_t* w2_t   = wts + 786432 + (size_t)l*65536;

        gemm_mfma_kernel<128><<<dim3(384/64, MM/128), 256, 0, stream>>>(
            hb, wqkv_t, bqkv + l*3*DIM, qkvb, 384, DIM, 0, 1);
        attn_mfma_kernel<<<BB*NHEADS*4, 512, 0, stream>>>(
            qkvb, rel_t + l*RELLEN, attno);
        pa_kernel<<<MM/32, 256, 0, stream>>>(
            attno, wo_t, bo + l*DIM, w1_t, w2_t, b1 + l*FFD, b2 + l*DIM,
            h, hb, ln1_g + l*DIM, ln1_b + l*DIM, ln2_g + l*DIM, ln2_b + l*DIM);
    }

    final_kernel<<<BB, 128, 0, stream>>>(h, final_g, final_b, cls_w, cls_b, (float*)d_out);
}